// Round 1
// baseline (1971.792 us; speedup 1.0000x reference)
//
#include <hip/hip_runtime.h>
#include <hip/hip_bf16.h>
#include <math.h>

#define N_NODES  100000
#define N_EDGES  1600000
#define N_GRAPHS 4096

__device__ __forceinline__ float lrelu(float x) { return x > 0.f ? x : 0.01f * x; }

// ---------------- histogram (counts into cnt via atomics) ----------------
__global__ void hist_kernel(const int* __restrict__ idx, unsigned* __restrict__ cnt, int n) {
    int i = blockIdx.x * 256 + threadIdx.x;
    if (i < n) atomicAdd(&cnt[idx[i]], 1u);
}

// ------- exclusive scan, single block 1024 thr, 4 elems/thread/chunk -------
__global__ __launch_bounds__(1024) void scan_kernel(const unsigned* __restrict__ in,
                                                    unsigned* __restrict__ out, int n) {
    __shared__ unsigned tmp[1024];
    __shared__ unsigned carry;
    int t = threadIdx.x;
    if (t == 0) carry = 0u;
    __syncthreads();
    for (int base = 0; base < n; base += 4096) {
        unsigned cin = carry;
        unsigned v[4]; unsigned s = 0u;
#pragma unroll
        for (int i = 0; i < 4; ++i) {
            int idx = base + t * 4 + i;
            v[i] = (idx < n) ? in[idx] : 0u;
            s += v[i];
        }
        tmp[t] = s;
        __syncthreads();
        for (int off = 1; off < 1024; off <<= 1) {
            unsigned x = (t >= off) ? tmp[t - off] : 0u;
            __syncthreads();
            tmp[t] += x;
            __syncthreads();
        }
        unsigned tot = tmp[1023];
        unsigned run = cin + (t ? tmp[t - 1] : 0u);
#pragma unroll
        for (int i = 0; i < 4; ++i) {
            int idx = base + t * 4 + i;
            if (idx < n) out[idx] = run;
            run += v[i];
        }
        __syncthreads();
        if (t == 0) carry = cin + tot;
        __syncthreads();
    }
    if (t == 0) out[n] = carry;
}

// ---------------- CSR fill (src list per dst node) ----------------
__global__ void fill_kernel(const int* __restrict__ ei, const unsigned* __restrict__ row_ptr,
                            unsigned* __restrict__ cursor, unsigned* __restrict__ col, int E) {
    int e = blockIdx.x * 256 + threadIdx.x;
    if (e >= E) return;
    int src = ei[e];
    int dst = ei[E + e];
    unsigned p = atomicAdd(&cursor[dst], 1u);
    col[row_ptr[dst] + p] = (unsigned)src;
}

// ---------------- aggregation: m[n] = T(h[n]) + sum_{j in N(n)} T(h[j]) ----
// T = identity, or per-column affine (post-GraphNorm) + leaky-relu.
// one wave per node, lane handles 2 columns (float2, 512B coalesced row read)
template<int D, bool ACT>
__global__ __launch_bounds__(256) void agg_kernel(const float* __restrict__ h, int ld_in,
        const unsigned* __restrict__ row_ptr, const unsigned* __restrict__ col,
        const float* __restrict__ aff, float* __restrict__ out, int ld_out, int n) {
    int node = blockIdx.x * 4 + (threadIdx.x >> 6);
    int lane = threadIdx.x & 63;
    constexpr int C2 = D / 2;
    if (node >= n || lane >= C2) return;
    int c = 2 * lane;
    float a0 = 1.f, a1 = 1.f, d0 = 0.f, d1 = 0.f;
    if (ACT) { a0 = aff[c]; a1 = aff[c + 1]; d0 = aff[128 + c]; d1 = aff[128 + c + 1]; }
    float2 v = *(const float2*)(h + (size_t)node * ld_in + c);
    float x0, x1;
    if (ACT) { x0 = lrelu(a0 * v.x + d0); x1 = lrelu(a1 * v.y + d1); }
    else     { x0 = v.x; x1 = v.y; }
    unsigned e0 = row_ptr[node], e1 = row_ptr[node + 1];
    for (unsigned e = e0; e < e1; ++e) {
        unsigned s = col[e];
        float2 u = *(const float2*)(h + (size_t)s * ld_in + c);
        if (ACT) { x0 += lrelu(a0 * u.x + d0); x1 += lrelu(a1 * u.y + d1); }
        else     { x0 += u.x; x1 += u.y; }
    }
    float2 o; o.x = x0; o.y = x1;
    *(float2*)(out + (size_t)node * ld_out + c) = o;
}

// ---------------- GEMM: out[M x 128] = T(A[M x K]) @ W[K x 128] + bias -----
// optional input affine+leaky (applied while staging A), optional fused
// column sum/sumsq stats (for the following GraphNorm).
// block = 256 thr, 64 rows x 128 cols, 4x8 register tile per thread.
// In-place safe (A==out, lda==128): full A tile staged to LDS before stores.
template<int K, bool AFF, bool STATS>
__global__ __launch_bounds__(256) void gemm_kernel(const float* A, int lda,
        const float* __restrict__ aff, const float* __restrict__ W,
        const float* __restrict__ bias, float* out, float* __restrict__ stats, int M) {
    __shared__ float As[64][K + 4];   // +4 pad: 2-way-max bank aliasing (free)
    __shared__ float Wt[128][36];     // transposed 32-k chunk, +4 pad
    __shared__ float ls[256];
    int t = threadIdx.x;
    int row0 = blockIdx.x * 64;
    constexpr int KV = K / 4;
    for (int l = t; l < 64 * KV; l += 256) {
        int r = l / KV, c4 = l - r * KV;
        int gr = row0 + r;
        float4 v = make_float4(0.f, 0.f, 0.f, 0.f);
        if (gr < M) v = *(const float4*)(A + (size_t)gr * lda + c4 * 4);
        if (AFF) {
            int c = c4 * 4;
            v.x = lrelu(aff[c + 0] * v.x + aff[128 + c + 0]);
            v.y = lrelu(aff[c + 1] * v.y + aff[128 + c + 1]);
            v.z = lrelu(aff[c + 2] * v.z + aff[128 + c + 2]);
            v.w = lrelu(aff[c + 3] * v.w + aff[128 + c + 3]);
        }
        *(float4*)&As[r][c4 * 4] = v;
    }
    if (STATS) ls[t] = 0.f;

    int tc = t & 15;   // column group: cols {tc + 16j}, j<8
    int tr = t >> 4;   // row group:    rows {4tr + i}, i<4
    float acc[4][8];
#pragma unroll
    for (int j = 0; j < 8; ++j) {
        float b = bias[tc + 16 * j];
#pragma unroll
        for (int i = 0; i < 4; ++i) acc[i][j] = b;
    }
    for (int ks = 0; ks < K; ks += 32) {
        int kc = (K - ks) < 32 ? (K - ks) : 32;
        __syncthreads();  // (1st iter: covers As staging + ls zero; later: Wt reuse)
        for (int l = t; l < kc * 32; l += 256) {
            int kr = l >> 5, c4 = l & 31;
            float4 v = *(const float4*)(W + (size_t)(ks + kr) * 128 + c4 * 4);
            Wt[c4 * 4 + 0][kr] = v.x;
            Wt[c4 * 4 + 1][kr] = v.y;
            Wt[c4 * 4 + 2][kr] = v.z;
            Wt[c4 * 4 + 3][kr] = v.w;
        }
        __syncthreads();
        for (int k4 = 0; k4 < kc; k4 += 4) {
            float4 a[4];
#pragma unroll
            for (int i = 0; i < 4; ++i) a[i] = *(const float4*)&As[4 * tr + i][ks + k4];
#pragma unroll
            for (int j = 0; j < 8; ++j) {
                float4 w = *(const float4*)&Wt[tc + 16 * j][k4];
#pragma unroll
                for (int i = 0; i < 4; ++i)
                    acc[i][j] += a[i].x * w.x + a[i].y * w.y + a[i].z * w.z + a[i].w * w.w;
            }
        }
    }
#pragma unroll
    for (int i = 0; i < 4; ++i) {
        int gr = row0 + 4 * tr + i;
        if (gr < M) {
#pragma unroll
            for (int j = 0; j < 8; ++j) out[(size_t)gr * 128 + tc + 16 * j] = acc[i][j];
        }
    }
    if (STATS) {
#pragma unroll
        for (int j = 0; j < 8; ++j) {
            float s = 0.f, s2 = 0.f;
#pragma unroll
            for (int i = 0; i < 4; ++i) {
                int gr = row0 + 4 * tr + i;
                if (gr < M) { float v = acc[i][j]; s += v; s2 += v * v; }
            }
            atomicAdd(&ls[tc + 16 * j], s);
            atomicAdd(&ls[128 + tc + 16 * j], s2);
        }
        __syncthreads();
        atomicAdd(&stats[t], ls[t]);
    }
}

// ---- stats -> affine: y = a*x + d  with a = w*rsqrt(var+eps), d = b - a*s*mean
__global__ __launch_bounds__(128) void finalize_kernel(const float* __restrict__ stats,
        const float* __restrict__ w, const float* __restrict__ b, const float* __restrict__ s,
        float* __restrict__ aff, float invN) {
    int c = threadIdx.x;
    float mean = stats[c] * invN;
    float ex2  = stats[128 + c] * invN;
    float sv   = s[c];
    float var  = ex2 - 2.f * sv * mean * mean + sv * sv * mean * mean;
    float a    = w[c] * rsqrtf(var + 1e-5f);
    aff[c]       = a;
    aff[128 + c] = b[c] - a * sv * mean;
}

// ---------------- pooling: mean / sum / max per graph (batch sorted) -------
__global__ __launch_bounds__(256) void pool_kernel(const float* __restrict__ h,
        const unsigned* __restrict__ gptr, float* __restrict__ gout, int G) {
    int g = blockIdx.x * 4 + (threadIdx.x >> 6);
    int lane = threadIdx.x & 63;
    if (g >= G) return;
    unsigned s = gptr[g], e = gptr[g + 1];
    int c = 2 * lane;
    float sx = 0.f, sy = 0.f, mx = -INFINITY, my = -INFINITY;
    for (unsigned n = s; n < e; ++n) {
        float2 v = *(const float2*)(h + (size_t)n * 128 + c);
        sx += v.x; sy += v.y;
        mx = fmaxf(mx, v.x); my = fmaxf(my, v.y);
    }
    float cnt = (float)(e - s);
    float inv = 1.f / fmaxf(cnt, 1.f);
    if (e == s) { mx = 0.f; my = 0.f; }
    float* go = gout + (size_t)g * 384;
    go[c] = sx * inv;       go[c + 1] = sy * inv;
    go[128 + c] = sx;       go[128 + c + 1] = sy;
    go[256 + c] = mx;       go[256 + c + 1] = my;
}

// ---------------- readout head: leaky(g@fc1+b1) @ fc2 + b2 ----------------
__global__ __launch_bounds__(64) void head_kernel(const float* __restrict__ gbuf,
        const float* __restrict__ w1, const float* __restrict__ b1,
        const float* __restrict__ w2, const float* __restrict__ b2,
        float* __restrict__ out, int G) {
    __shared__ float y[64];
    int g = blockIdx.x, t = threadIdx.x;
    const float* row = gbuf + (size_t)g * 384;
    float acc = b1[t];
    for (int k = 0; k < 384; ++k) acc += row[k] * w1[(size_t)k * 64 + t];
    y[t] = lrelu(acc);
    __syncthreads();
    if (t < 3) {
        float o = b2[t];
        for (int k = 0; k < 64; ++k) o += y[k] * w2[k * 3 + t];
        out[(size_t)g * 3 + t] = o;
    }
}

extern "C" void kernel_launch(void* const* d_in, const int* in_sizes, int n_in,
                              void* d_out, int out_size, void* d_ws, size_t ws_size,
                              hipStream_t stream) {
    const float* x       = (const float*)d_in[0];
    const float* W1_0    = (const float*)d_in[2];
    const float* b1_0    = (const float*)d_in[3];
    const float* W1_rest = (const float*)d_in[4];
    const float* b1_rest = (const float*)d_in[5];
    const float* gn_w    = (const float*)d_in[6];
    const float* gn_b    = (const float*)d_in[7];
    const float* gn_s    = (const float*)d_in[8];
    const float* W2      = (const float*)d_in[9];
    const float* b2      = (const float*)d_in[10];
    const float* pn_w    = (const float*)d_in[11];
    const float* pn_b    = (const float*)d_in[12];
    const float* pn_s    = (const float*)d_in[13];
    const float* fc1W    = (const float*)d_in[14];
    const float* fc1b    = (const float*)d_in[15];
    const float* fc2W    = (const float*)d_in[16];
    const float* fc2b    = (const float*)d_in[17];
    const int*   ei      = (const int*)d_in[18];
    const int*   batch   = (const int*)d_in[19];
    float* outp = (float*)d_out;

    const int N = N_NODES, E = N_EDGES, G = N_GRAPHS;
    char* w = (char*)d_ws;
    auto alloc = [&](size_t bytes) -> char* {
        char* p = w; w += (bytes + 255) & ~(size_t)255; return p;
    };
    float*    buf0    = (float*)alloc((size_t)N * 128 * 4);
    float*    buf1    = (float*)alloc((size_t)N * 128 * 4);
    unsigned* row_ptr = (unsigned*)alloc((size_t)(N + 1) * 4);
    unsigned* deg     = (unsigned*)alloc((size_t)N * 4);
    unsigned* cursor  = (unsigned*)alloc((size_t)N * 4);
    unsigned* colb    = (unsigned*)alloc((size_t)E * 4);
    unsigned* ghist   = (unsigned*)alloc((size_t)G * 4);
    unsigned* gptr    = (unsigned*)alloc((size_t)(G + 1) * 4);
    float*    stats   = (float*)alloc(256 * 4);
    float*    aff_gn  = (float*)alloc(256 * 4);
    float*    aff_pn  = (float*)alloc(256 * 4);
    float*    gbuf    = (float*)alloc((size_t)G * 384 * 4);

    hipMemsetAsync(deg, 0, (size_t)N * 4, stream);
    hipMemsetAsync(cursor, 0, (size_t)N * 4, stream);
    hipMemsetAsync(ghist, 0, (size_t)G * 4, stream);

    // CSR over dst, and graph segmentation over (sorted) batch
    hist_kernel<<<(E + 255) / 256, 256, 0, stream>>>(ei + E, deg, E);
    scan_kernel<<<1, 1024, 0, stream>>>(deg, row_ptr, N);
    fill_kernel<<<(E + 255) / 256, 256, 0, stream>>>(ei, row_ptr, cursor, colb, E);
    hist_kernel<<<(N + 255) / 256, 256, 0, stream>>>(batch, ghist, N);
    scan_kernel<<<1, 1024, 0, stream>>>(ghist, gptr, G);

    const float invN = 1.f / (float)N;
    int gemm_grid = (N + 63) / 64;
    int agg_grid  = (N + 3) / 4;

    // ---- layer 0 (input x is 48-dim, no preceding norm/act) ----
    agg_kernel<48, false><<<agg_grid, 256, 0, stream>>>(x, 48, row_ptr, colb, nullptr, buf1, 128, N);
    hipMemsetAsync(stats, 0, 1024, stream);
    gemm_kernel<48, false, true><<<gemm_grid, 256, 0, stream>>>(buf1, 128, nullptr, W1_0, b1_0, buf1, stats, N);
    finalize_kernel<<<1, 128, 0, stream>>>(stats, gn_w, gn_b, gn_s, aff_gn, invN);
    hipMemsetAsync(stats, 0, 1024, stream);
    gemm_kernel<128, true, true><<<gemm_grid, 256, 0, stream>>>(buf1, 128, aff_gn, W2, b2, buf0, stats, N);
    finalize_kernel<<<1, 128, 0, stream>>>(stats, pn_w, pn_b, pn_s, aff_pn, invN);

    // ---- layers 1..3 ----
    for (int i = 1; i < 4; ++i) {
        agg_kernel<128, true><<<agg_grid, 256, 0, stream>>>(buf0, 128, row_ptr, colb, aff_pn, buf1, 128, N);
        hipMemsetAsync(stats, 0, 1024, stream);
        gemm_kernel<128, false, true><<<gemm_grid, 256, 0, stream>>>(buf1, 128, nullptr,
                W1_rest + (size_t)(i - 1) * 128 * 128, b1_rest + (size_t)(i - 1) * 128, buf1, stats, N);
        finalize_kernel<<<1, 128, 0, stream>>>(stats, gn_w + i * 128, gn_b + i * 128, gn_s + i * 128, aff_gn, invN);
        if (i < 3) {
            hipMemsetAsync(stats, 0, 1024, stream);
            gemm_kernel<128, true, true><<<gemm_grid, 256, 0, stream>>>(buf1, 128, aff_gn,
                    W2 + (size_t)i * 128 * 128, b2 + (size_t)i * 128, buf0, stats, N);
            finalize_kernel<<<1, 128, 0, stream>>>(stats, pn_w + i * 128, pn_b + i * 128, pn_s + i * 128, aff_pn, invN);
        } else {
            gemm_kernel<128, true, false><<<gemm_grid, 256, 0, stream>>>(buf1, 128, aff_gn,
                    W2 + (size_t)i * 128 * 128, b2 + (size_t)i * 128, buf0, nullptr, N);
        }
    }

    pool_kernel<<<(G + 3) / 4, 256, 0, stream>>>(buf0, gptr, gbuf, G);
    head_kernel<<<G, 64, 0, stream>>>(gbuf, fc1W, fc1b, fc2W, fc2b, outp, G);
}

// Round 2
// 1817.349 us; speedup vs baseline: 1.0850x; 1.0850x over previous
//
#include <hip/hip_runtime.h>
#include <hip/hip_bf16.h>
#include <math.h>

#define N_NODES  100000
#define N_EDGES  1600000
#define N_GRAPHS 4096

typedef __attribute__((ext_vector_type(4))) float f32x4;
typedef __attribute__((ext_vector_type(8))) short bf16x8;

__device__ __forceinline__ float lrelu(float x) { return x > 0.f ? x : 0.01f * x; }

__device__ __forceinline__ unsigned short f2bf(float f) {
    unsigned u = __float_as_uint(f);
    unsigned r = (u + 0x7FFFu + ((u >> 16) & 1u)) >> 16;
    return (unsigned short)r;
}
__device__ __forceinline__ float bf2f(unsigned short h) {
    return __uint_as_float(((unsigned)h) << 16);
}

// ---------------- histogram (counts into cnt via atomics) ----------------
__global__ void hist_kernel(const int* __restrict__ idx, unsigned* __restrict__ cnt, int n) {
    int i = blockIdx.x * 256 + threadIdx.x;
    if (i < n) atomicAdd(&cnt[idx[i]], 1u);
}

// ------- exclusive scan, single block 1024 thr, 4 elems/thread/chunk -------
__global__ __launch_bounds__(1024) void scan_kernel(const unsigned* __restrict__ in,
                                                    unsigned* __restrict__ out, int n) {
    __shared__ unsigned tmp[1024];
    __shared__ unsigned carry;
    int t = threadIdx.x;
    if (t == 0) carry = 0u;
    __syncthreads();
    for (int base = 0; base < n; base += 4096) {
        unsigned cin = carry;
        unsigned v[4]; unsigned s = 0u;
#pragma unroll
        for (int i = 0; i < 4; ++i) {
            int idx = base + t * 4 + i;
            v[i] = (idx < n) ? in[idx] : 0u;
            s += v[i];
        }
        tmp[t] = s;
        __syncthreads();
        for (int off = 1; off < 1024; off <<= 1) {
            unsigned x = (t >= off) ? tmp[t - off] : 0u;
            __syncthreads();
            tmp[t] += x;
            __syncthreads();
        }
        unsigned tot = tmp[1023];
        unsigned run = cin + (t ? tmp[t - 1] : 0u);
#pragma unroll
        for (int i = 0; i < 4; ++i) {
            int idx = base + t * 4 + i;
            if (idx < n) out[idx] = run;
            run += v[i];
        }
        __syncthreads();
        if (t == 0) carry = cin + tot;
        __syncthreads();
    }
    if (t == 0) out[n] = carry;
}

// ---------------- CSR fill (src list per dst node) ----------------
__global__ void fill_kernel(const int* __restrict__ ei, const unsigned* __restrict__ row_ptr,
                            unsigned* __restrict__ cursor, unsigned* __restrict__ col, int E) {
    int e = blockIdx.x * 256 + threadIdx.x;
    if (e >= E) return;
    int src = ei[e];
    int dst = ei[E + e];
    unsigned p = atomicAdd(&cursor[dst], 1u);
    col[row_ptr[dst] + p] = (unsigned)src;
}

// ---------------- aggregation: m[n] = T(h[n]) + sum_{j in N(n)} T(h[j]) ----
template<int D, bool ACT>
__global__ __launch_bounds__(256) void agg_kernel(const float* __restrict__ h, int ld_in,
        const unsigned* __restrict__ row_ptr, const unsigned* __restrict__ col,
        const float* __restrict__ aff, float* __restrict__ out, int ld_out, int n) {
    int node = blockIdx.x * 4 + (threadIdx.x >> 6);
    int lane = threadIdx.x & 63;
    constexpr int C2 = D / 2;
    if (node >= n || lane >= C2) return;
    int c = 2 * lane;
    float a0 = 1.f, a1 = 1.f, d0 = 0.f, d1 = 0.f;
    if (ACT) { a0 = aff[c]; a1 = aff[c + 1]; d0 = aff[128 + c]; d1 = aff[128 + c + 1]; }
    float2 v = *(const float2*)(h + (size_t)node * ld_in + c);
    float x0, x1;
    if (ACT) { x0 = lrelu(a0 * v.x + d0); x1 = lrelu(a1 * v.y + d1); }
    else     { x0 = v.x; x1 = v.y; }
    unsigned e0 = row_ptr[node], e1 = row_ptr[node + 1];
    for (unsigned e = e0; e < e1; ++e) {
        unsigned s = col[e];
        float2 u = *(const float2*)(h + (size_t)s * ld_in + c);
        if (ACT) { x0 += lrelu(a0 * u.x + d0); x1 += lrelu(a1 * u.y + d1); }
        else     { x0 += u.x; x1 += u.y; }
    }
    float2 o; o.x = x0; o.y = x1;
    *(float2*)(out + (size_t)node * ld_out + c) = o;
}

// ---- W preprocess: transpose + hi/lo bf16 split into wt scratch ----------
// wt layout per GEMM g (stride 32768 shorts): hi[n][k] (128x128) then lo[n][k].
// g0=W1_0 (K=48, zero-padded), odd g=W2[(g-1)/2], even g>=2=W1_rest[(g-2)/2].
__global__ __launch_bounds__(256) void wsplit_kernel(const float* __restrict__ W1_0,
        const float* __restrict__ W1_rest, const float* __restrict__ W2,
        unsigned short* __restrict__ wt) {
    int g = blockIdx.y;
    int i = blockIdx.x * 256 + threadIdx.x;   // i = n*128 + k
    int n = i >> 7, k = i & 127;
    float v = 0.f;
    if (g == 0) { if (k < 48) v = W1_0[k * 128 + n]; }
    else if (g & 1) v = W2[(size_t)((g - 1) >> 1) * 16384 + k * 128 + n];
    else            v = W1_rest[(size_t)((g - 2) >> 1) * 16384 + k * 128 + n];
    unsigned short hi = f2bf(v);
    unsigned short lo = f2bf(v - bf2f(hi));
    size_t base = (size_t)g * 32768;
    wt[base + i] = hi;
    wt[base + 16384 + i] = lo;
}

// ---------------- MFMA GEMM: out[M x 128] = T(A[M x K]) @ W + bias --------
// hi/lo bf16 split (3 MFMA terms) => f32-class accuracy, ~3x bf16 FLOPs.
// block = 256 thr = 4 waves; wave handles 16 rows x 128 cols.
// A loaded straight from global into fragments (no LDS), W from wt scratch.
// In-place safe: a wave reads only its own 16 rows, stores the same rows.
template<int K, bool AFF, bool STATS>
__global__ __launch_bounds__(256) void mgemm_kernel(const float* __restrict__ A,
        const float* __restrict__ aff, const unsigned short* __restrict__ Wt,
        const float* __restrict__ bias, float* __restrict__ out,
        float* __restrict__ stats, int M) {
    constexpr int KS = (K + 31) / 32;
    __shared__ float ls[256];
    int t = threadIdx.x;
    if (STATS) { ls[t] = 0.f; __syncthreads(); }
    int lane = t & 63, wid = t >> 6;
    int m = lane & 15, kg = lane >> 4;
    int rowBase = blockIdx.x * 64 + wid * 16;
    int arow = rowBase + m;
    bool rowOK = arow < M;

    union U8 { bf16x8 v; unsigned short u[8]; };
    U8 ahi[KS], alo[KS];
#pragma unroll
    for (int ks = 0; ks < KS; ++ks) {
        int k0 = ks * 32 + kg * 8;
        float x[8];
        if (rowOK && k0 < K) {
            f32x4 p = *(const f32x4*)(A + (size_t)arow * 128 + k0);
            f32x4 q = *(const f32x4*)(A + (size_t)arow * 128 + k0 + 4);
            x[0] = p[0]; x[1] = p[1]; x[2] = p[2]; x[3] = p[3];
            x[4] = q[0]; x[5] = q[1]; x[6] = q[2]; x[7] = q[3];
        } else {
#pragma unroll
            for (int j = 0; j < 8; ++j) x[j] = 0.f;
        }
        if (AFF) {
#pragma unroll
            for (int j = 0; j < 8; ++j)
                x[j] = lrelu(aff[k0 + j] * x[j] + aff[128 + k0 + j]);
        }
#pragma unroll
        for (int j = 0; j < 8; ++j) {
            unsigned short h = f2bf(x[j]);
            ahi[ks].u[j] = h;
            alo[ks].u[j] = f2bf(x[j] - bf2f(h));
        }
    }

    f32x4 acc[8];
#pragma unroll
    for (int j = 0; j < 8; ++j) {
        float b = bias[16 * j + m];
        acc[j] = (f32x4){b, b, b, b};
    }

#pragma unroll
    for (int j = 0; j < 8; ++j) {
        int n = 16 * j + m;
#pragma unroll
        for (int ks = 0; ks < KS; ++ks) {
            int k0 = ks * 32 + kg * 8;
            bf16x8 whi = *(const bf16x8*)(Wt + (size_t)n * 128 + k0);
            bf16x8 wlo = *(const bf16x8*)(Wt + 16384 + (size_t)n * 128 + k0);
            acc[j] = __builtin_amdgcn_mfma_f32_16x16x32_bf16(ahi[ks].v, whi, acc[j], 0, 0, 0);
            acc[j] = __builtin_amdgcn_mfma_f32_16x16x32_bf16(alo[ks].v, whi, acc[j], 0, 0, 0);
            acc[j] = __builtin_amdgcn_mfma_f32_16x16x32_bf16(ahi[ks].v, wlo, acc[j], 0, 0, 0);
        }
    }

    // C/D layout: col = lane&15 (=m), row = kg*4 + reg   [m89-verified]
#pragma unroll
    for (int j = 0; j < 8; ++j) {
        int col = 16 * j + m;
#pragma unroll
        for (int r = 0; r < 4; ++r) {
            int gr = rowBase + kg * 4 + r;
            if (gr < M) out[(size_t)gr * 128 + col] = acc[j][r];
        }
    }

    if (STATS) {
#pragma unroll
        for (int j = 0; j < 8; ++j) {
            float s = 0.f, s2 = 0.f;
#pragma unroll
            for (int r = 0; r < 4; ++r) {
                int gr = rowBase + kg * 4 + r;
                if (gr < M) { float v = acc[j][r]; s += v; s2 += v * v; }
            }
            atomicAdd(&ls[16 * j + m], s);
            atomicAdd(&ls[128 + 16 * j + m], s2);
        }
        __syncthreads();
        atomicAdd(&stats[t], ls[t]);
    }
}

// ---- stats -> affine: y = a*x + d  with a = w*rsqrt(var+eps), d = b - a*s*mean
__global__ __launch_bounds__(128) void finalize_kernel(const float* __restrict__ stats,
        const float* __restrict__ w, const float* __restrict__ b, const float* __restrict__ s,
        float* __restrict__ aff, float invN) {
    int c = threadIdx.x;
    float mean = stats[c] * invN;
    float ex2  = stats[128 + c] * invN;
    float sv   = s[c];
    float var  = ex2 - 2.f * sv * mean * mean + sv * sv * mean * mean;
    float a    = w[c] * rsqrtf(var + 1e-5f);
    aff[c]       = a;
    aff[128 + c] = b[c] - a * sv * mean;
}

// ---------------- pooling: mean / sum / max per graph (batch sorted) -------
__global__ __launch_bounds__(256) void pool_kernel(const float* __restrict__ h,
        const unsigned* __restrict__ gptr, float* __restrict__ gout, int G) {
    int g = blockIdx.x * 4 + (threadIdx.x >> 6);
    int lane = threadIdx.x & 63;
    if (g >= G) return;
    unsigned s = gptr[g], e = gptr[g + 1];
    int c = 2 * lane;
    float sx = 0.f, sy = 0.f, mx = -INFINITY, my = -INFINITY;
    for (unsigned n = s; n < e; ++n) {
        float2 v = *(const float2*)(h + (size_t)n * 128 + c);
        sx += v.x; sy += v.y;
        mx = fmaxf(mx, v.x); my = fmaxf(my, v.y);
    }
    float cnt = (float)(e - s);
    float inv = 1.f / fmaxf(cnt, 1.f);
    if (e == s) { mx = 0.f; my = 0.f; }
    float* go = gout + (size_t)g * 384;
    go[c] = sx * inv;       go[c + 1] = sy * inv;
    go[128 + c] = sx;       go[128 + c + 1] = sy;
    go[256 + c] = mx;       go[256 + c + 1] = my;
}

// ---------------- readout head: leaky(g@fc1+b1) @ fc2 + b2 ----------------
__global__ __launch_bounds__(64) void head_kernel(const float* __restrict__ gbuf,
        const float* __restrict__ w1, const float* __restrict__ b1,
        const float* __restrict__ w2, const float* __restrict__ b2,
        float* __restrict__ out, int G) {
    __shared__ float y[64];
    int g = blockIdx.x, t = threadIdx.x;
    const float* row = gbuf + (size_t)g * 384;
    float acc = b1[t];
    for (int k = 0; k < 384; ++k) acc += row[k] * w1[(size_t)k * 64 + t];
    y[t] = lrelu(acc);
    __syncthreads();
    if (t < 3) {
        float o = b2[t];
        for (int k = 0; k < 64; ++k) o += y[k] * w2[k * 3 + t];
        out[(size_t)g * 3 + t] = o;
    }
}

extern "C" void kernel_launch(void* const* d_in, const int* in_sizes, int n_in,
                              void* d_out, int out_size, void* d_ws, size_t ws_size,
                              hipStream_t stream) {
    const float* x       = (const float*)d_in[0];
    const float* W1_0    = (const float*)d_in[2];
    const float* b1_0    = (const float*)d_in[3];
    const float* W1_rest = (const float*)d_in[4];
    const float* b1_rest = (const float*)d_in[5];
    const float* gn_w    = (const float*)d_in[6];
    const float* gn_b    = (const float*)d_in[7];
    const float* gn_s    = (const float*)d_in[8];
    const float* W2      = (const float*)d_in[9];
    const float* b2      = (const float*)d_in[10];
    const float* pn_w    = (const float*)d_in[11];
    const float* pn_b    = (const float*)d_in[12];
    const float* pn_s    = (const float*)d_in[13];
    const float* fc1W    = (const float*)d_in[14];
    const float* fc1b    = (const float*)d_in[15];
    const float* fc2W    = (const float*)d_in[16];
    const float* fc2b    = (const float*)d_in[17];
    const int*   ei      = (const int*)d_in[18];
    const int*   batch   = (const int*)d_in[19];
    float* outp = (float*)d_out;

    const int N = N_NODES, E = N_EDGES, G = N_GRAPHS;
    char* w = (char*)d_ws;
    auto alloc = [&](size_t bytes) -> char* {
        char* p = w; w += (bytes + 255) & ~(size_t)255; return p;
    };
    float*    buf0    = (float*)alloc((size_t)N * 128 * 4);
    float*    buf1    = (float*)alloc((size_t)N * 128 * 4);
    unsigned* row_ptr = (unsigned*)alloc((size_t)(N + 1) * 4);
    unsigned* deg     = (unsigned*)alloc((size_t)N * 4);
    unsigned* cursor  = (unsigned*)alloc((size_t)N * 4);
    unsigned* colb    = (unsigned*)alloc((size_t)E * 4);
    unsigned* ghist   = (unsigned*)alloc((size_t)G * 4);
    unsigned* gptr    = (unsigned*)alloc((size_t)(G + 1) * 4);
    float*    stats   = (float*)alloc(256 * 4);
    float*    aff_gn  = (float*)alloc(256 * 4);
    float*    aff_pn  = (float*)alloc(256 * 4);
    float*    gbuf    = (float*)alloc((size_t)G * 384 * 4);
    unsigned short* wt = (unsigned short*)alloc((size_t)8 * 32768 * 2);

    hipMemsetAsync(deg, 0, (size_t)N * 4, stream);
    hipMemsetAsync(cursor, 0, (size_t)N * 4, stream);
    hipMemsetAsync(ghist, 0, (size_t)G * 4, stream);

    // CSR over dst, graph segmentation, W preprocess
    hist_kernel<<<(E + 255) / 256, 256, 0, stream>>>(ei + E, deg, E);
    scan_kernel<<<1, 1024, 0, stream>>>(deg, row_ptr, N);
    fill_kernel<<<(E + 255) / 256, 256, 0, stream>>>(ei, row_ptr, cursor, colb, E);
    hist_kernel<<<(N + 255) / 256, 256, 0, stream>>>(batch, ghist, N);
    scan_kernel<<<1, 1024, 0, stream>>>(ghist, gptr, G);
    wsplit_kernel<<<dim3(64, 8), 256, 0, stream>>>(W1_0, W1_rest, W2, wt);

    const float invN = 1.f / (float)N;
    int gemm_grid = (N + 63) / 64;
    int agg_grid  = (N + 3) / 4;

    // ---- layer 0 (input x is 48-dim, no preceding norm/act) ----
    agg_kernel<48, false><<<agg_grid, 256, 0, stream>>>(x, 48, row_ptr, colb, nullptr, buf1, 128, N);
    hipMemsetAsync(stats, 0, 1024, stream);
    mgemm_kernel<48, false, true><<<gemm_grid, 256, 0, stream>>>(buf1, nullptr, wt, b1_0, buf1, stats, N);
    finalize_kernel<<<1, 128, 0, stream>>>(stats, gn_w, gn_b, gn_s, aff_gn, invN);
    hipMemsetAsync(stats, 0, 1024, stream);
    mgemm_kernel<128, true, true><<<gemm_grid, 256, 0, stream>>>(buf1, aff_gn, wt + 1 * 32768, b2, buf0, stats, N);
    finalize_kernel<<<1, 128, 0, stream>>>(stats, pn_w, pn_b, pn_s, aff_pn, invN);

    // ---- layers 1..3 ----
    for (int i = 1; i < 4; ++i) {
        agg_kernel<128, true><<<agg_grid, 256, 0, stream>>>(buf0, 128, row_ptr, colb, aff_pn, buf1, 128, N);
        hipMemsetAsync(stats, 0, 1024, stream);
        mgemm_kernel<128, false, true><<<gemm_grid, 256, 0, stream>>>(buf1, nullptr,
                wt + (size_t)(2 * i) * 32768, b1_rest + (size_t)(i - 1) * 128, buf1, stats, N);
        finalize_kernel<<<1, 128, 0, stream>>>(stats, gn_w + i * 128, gn_b + i * 128, gn_s + i * 128, aff_gn, invN);
        if (i < 3) {
            hipMemsetAsync(stats, 0, 1024, stream);
            mgemm_kernel<128, true, true><<<gemm_grid, 256, 0, stream>>>(buf1, aff_gn,
                    wt + (size_t)(2 * i + 1) * 32768, b2 + (size_t)i * 128, buf0, stats, N);
            finalize_kernel<<<1, 128, 0, stream>>>(stats, pn_w + i * 128, pn_b + i * 128, pn_s + i * 128, aff_pn, invN);
        } else {
            mgemm_kernel<128, true, false><<<gemm_grid, 256, 0, stream>>>(buf1, aff_gn,
                    wt + (size_t)7 * 32768, b2 + (size_t)3 * 128, buf0, nullptr, N);
        }
    }

    pool_kernel<<<(G + 3) / 4, 256, 0, stream>>>(buf0, gptr, gbuf, G);
    head_kernel<<<G, 64, 0, stream>>>(gbuf, fc1W, fc1b, fc2W, fc2b, outp, G);
}

// Round 3
// 1450.625 us; speedup vs baseline: 1.3593x; 1.2528x over previous
//
#include <hip/hip_runtime.h>
#include <hip/hip_bf16.h>
#include <math.h>

#define N_NODES  100000
#define N_EDGES  1600000
#define N_GRAPHS 4096

typedef __attribute__((ext_vector_type(4))) float f32x4;
typedef __attribute__((ext_vector_type(8))) short bf16x8;

__device__ __forceinline__ float lrelu(float x) { return x > 0.f ? x : 0.01f * x; }

__device__ __forceinline__ unsigned short f2bf(float f) {
    unsigned u = __float_as_uint(f);
    unsigned r = (u + 0x7FFFu + ((u >> 16) & 1u)) >> 16;
    return (unsigned short)r;
}
__device__ __forceinline__ float bf2f(unsigned short h) {
    return __uint_as_float(((unsigned)h) << 16);
}

// ---------------- histogram (counts into cnt via atomics) ----------------
__global__ void hist_kernel(const int* __restrict__ idx, unsigned* __restrict__ cnt, int n) {
    int i = blockIdx.x * 256 + threadIdx.x;
    if (i < n) atomicAdd(&cnt[idx[i]], 1u);
}

// ------- exclusive scan, single block 1024 thr, shuffle-based -------------
__global__ __launch_bounds__(1024) void scan_kernel(const unsigned* __restrict__ in,
                                                    unsigned* __restrict__ out, int n) {
    __shared__ unsigned wsum[16];
    __shared__ unsigned carry_s;
    int t = threadIdx.x, lane = t & 63, wv = t >> 6;
    if (t == 0) carry_s = 0u;
    __syncthreads();
    for (int base = 0; base < n; base += 4096) {
        unsigned carry = carry_s;
        unsigned v[4]; unsigned s = 0u;
#pragma unroll
        for (int i = 0; i < 4; ++i) {
            int idx = base + t * 4 + i;
            v[i] = (idx < n) ? in[idx] : 0u;
            s += v[i];
        }
        // inclusive wave scan of s
        unsigned ps = s;
#pragma unroll
        for (int off = 1; off < 64; off <<= 1) {
            unsigned x = __shfl_up(ps, off, 64);
            if (lane >= off) ps += x;
        }
        if (lane == 63) wsum[wv] = ps;
        __syncthreads();
        if (wv == 0 && lane < 16) {
            unsigned pw = wsum[lane];
#pragma unroll
            for (int off = 1; off < 16; off <<= 1) {
                unsigned x = __shfl_up(pw, off, 64);
                if (lane >= off) pw += x;
            }
            wsum[lane] = pw;   // inclusive over wave sums
        }
        __syncthreads();
        unsigned wbase = wv ? wsum[wv - 1] : 0u;
        unsigned run = carry + wbase + (ps - s);
#pragma unroll
        for (int i = 0; i < 4; ++i) {
            int idx = base + t * 4 + i;
            if (idx < n) out[idx] = run;
            run += v[i];
        }
        unsigned total = wsum[15];
        __syncthreads();
        if (t == 0) carry_s = carry + total;
        __syncthreads();
    }
    if (t == 0) out[n] = carry_s;
}

// ---------------- CSR fill (src list per dst node) ----------------
__global__ void fill_kernel(const int* __restrict__ ei, const unsigned* __restrict__ row_ptr,
                            unsigned* __restrict__ cursor, unsigned* __restrict__ col, int E) {
    int e = blockIdx.x * 256 + threadIdx.x;
    if (e >= E) return;
    int src = ei[e];
    int dst = ei[E + e];
    unsigned p = atomicAdd(&cursor[dst], 1u);
    col[row_ptr[dst] + p] = (unsigned)src;
}

// ---------------- cast x (f32) -> bf16 shadow ----------------
__global__ void cast_kernel(const float* __restrict__ in, unsigned short* __restrict__ outb, int n) {
    int i = blockIdx.x * 256 + threadIdx.x;
    if (i < n) outb[i] = f2bf(in[i]);
}

// ---------------- aggregation: m[n] = T(h[n]) + sum_{j in N(n)} T(h[j]) ----
// h gathered from a bf16 shadow (halves fabric bytes); out written f32.
// T = identity, or GraphNorm affine (computed inline from stats) + leaky-relu.
// one wave per node, lane handles 2 columns (4B/lane loads); 4-deep edge
// unroll with independent accumulators for memory-level parallelism.
template<int D, bool ACT>
__global__ __launch_bounds__(256) void agg_kernel(const unsigned short* __restrict__ hb, int ld_in,
        const unsigned* __restrict__ row_ptr, const unsigned* __restrict__ col,
        const float* __restrict__ stats, const float* __restrict__ wp,
        const float* __restrict__ bp, const float* __restrict__ sp, float invN,
        float* __restrict__ out, int ld_out, int n) {
    int node = blockIdx.x * 4 + (threadIdx.x >> 6);
    int lane = threadIdx.x & 63;
    constexpr int C2 = D / 2;
    if (node >= n || lane >= C2) return;
    int c = 2 * lane;
    float a0 = 1.f, a1 = 1.f, d0 = 0.f, d1 = 0.f;
    if (ACT) {
        float mean0 = stats[c] * invN,       mean1 = stats[c + 1] * invN;
        float ex0   = stats[128 + c] * invN, ex1   = stats[129 + c] * invN;
        float s0 = sp[c], s1 = sp[c + 1];
        float var0 = ex0 - 2.f * s0 * mean0 * mean0 + s0 * s0 * mean0 * mean0;
        float var1 = ex1 - 2.f * s1 * mean1 * mean1 + s1 * s1 * mean1 * mean1;
        a0 = wp[c] * rsqrtf(var0 + 1e-5f);
        a1 = wp[c + 1] * rsqrtf(var1 + 1e-5f);
        d0 = bp[c] - a0 * s0 * mean0;
        d1 = bp[c + 1] - a1 * s1 * mean1;
    }
    const unsigned* rowp = (const unsigned*)(hb);
#define LOADU(src) *(const unsigned*)(hb + (size_t)(src) * ld_in + c)
#define TX(u)  (ACT ? lrelu(a0 * bf2f((unsigned short)((u) & 0xffffu)) + d0) : bf2f((unsigned short)((u) & 0xffffu)))
#define TY(u)  (ACT ? lrelu(a1 * bf2f((unsigned short)((u) >> 16)) + d1)    : bf2f((unsigned short)((u) >> 16)))
    unsigned su = LOADU(node);
    float x0 = TX(su), x1 = TY(su);
    float y0 = 0.f, y1 = 0.f, z0 = 0.f, z1 = 0.f, q0 = 0.f, q1 = 0.f;
    unsigned e0 = row_ptr[node], e1 = row_ptr[node + 1];
    unsigned e = e0;
    for (; e + 4 <= e1; e += 4) {
        unsigned s0i = col[e], s1i = col[e + 1], s2i = col[e + 2], s3i = col[e + 3];
        unsigned u0 = LOADU(s0i), u1 = LOADU(s1i), u2 = LOADU(s2i), u3 = LOADU(s3i);
        x0 += TX(u0); x1 += TY(u0);
        y0 += TX(u1); y1 += TY(u1);
        z0 += TX(u2); z1 += TY(u2);
        q0 += TX(u3); q1 += TY(u3);
    }
    for (; e < e1; ++e) {
        unsigned u = LOADU(col[e]);
        x0 += TX(u); x1 += TY(u);
    }
#undef LOADU
#undef TX
#undef TY
    float2 o;
    o.x = (x0 + y0) + (z0 + q0);
    o.y = (x1 + y1) + (z1 + q1);
    (void)rowp;
    *(float2*)(out + (size_t)node * ld_out + c) = o;
}

// ---- W preprocess: transpose + hi/lo bf16 split into wt scratch ----------
__global__ __launch_bounds__(256) void wsplit_kernel(const float* __restrict__ W1_0,
        const float* __restrict__ W1_rest, const float* __restrict__ W2,
        unsigned short* __restrict__ wt) {
    int g = blockIdx.y;
    int i = blockIdx.x * 256 + threadIdx.x;   // i = n*128 + k
    int n = i >> 7, k = i & 127;
    float v = 0.f;
    if (g == 0) { if (k < 48) v = W1_0[k * 128 + n]; }
    else if (g & 1) v = W2[(size_t)((g - 1) >> 1) * 16384 + k * 128 + n];
    else            v = W1_rest[(size_t)((g - 2) >> 1) * 16384 + k * 128 + n];
    unsigned short hi = f2bf(v);
    unsigned short lo = f2bf(v - bf2f(hi));
    size_t base = (size_t)g * 32768;
    wt[base + i] = hi;
    wt[base + 16384 + i] = lo;
}

// ---------------- MFMA GEMM: out[M x 128] = T(A[M x K]) @ W + bias --------
// hi/lo bf16 split (3 MFMA terms) => f32-class accuracy.
// block = 256 thr = 4 waves; wave handles 16 rows x 128 cols.
// BF16OUT: also write a bf16 shadow of the output (next layer's gather src).
template<int K, bool AFF, bool STATS, bool BF16OUT>
__global__ __launch_bounds__(256) void mgemm_kernel(const float* __restrict__ A,
        const float* __restrict__ aff, const unsigned short* __restrict__ Wt,
        const float* __restrict__ bias, float* __restrict__ out,
        unsigned short* __restrict__ outb, float* __restrict__ stats, int M) {
    constexpr int KS = (K + 31) / 32;
    __shared__ float ls[256];
    int t = threadIdx.x;
    if (STATS) { ls[t] = 0.f; __syncthreads(); }
    int lane = t & 63, wid = t >> 6;
    int m = lane & 15, kg = lane >> 4;
    int rowBase = blockIdx.x * 64 + wid * 16;
    int arow = rowBase + m;
    bool rowOK = arow < M;

    union U8 { bf16x8 v; unsigned short u[8]; };
    U8 ahi[KS], alo[KS];
#pragma unroll
    for (int ks = 0; ks < KS; ++ks) {
        int k0 = ks * 32 + kg * 8;
        float x[8];
        if (rowOK && k0 < K) {
            f32x4 p = *(const f32x4*)(A + (size_t)arow * 128 + k0);
            f32x4 q = *(const f32x4*)(A + (size_t)arow * 128 + k0 + 4);
            x[0] = p[0]; x[1] = p[1]; x[2] = p[2]; x[3] = p[3];
            x[4] = q[0]; x[5] = q[1]; x[6] = q[2]; x[7] = q[3];
        } else {
#pragma unroll
            for (int j = 0; j < 8; ++j) x[j] = 0.f;
        }
        if (AFF) {
#pragma unroll
            for (int j = 0; j < 8; ++j)
                x[j] = lrelu(aff[k0 + j] * x[j] + aff[128 + k0 + j]);
        }
#pragma unroll
        for (int j = 0; j < 8; ++j) {
            unsigned short h = f2bf(x[j]);
            ahi[ks].u[j] = h;
            alo[ks].u[j] = f2bf(x[j] - bf2f(h));
        }
    }

    f32x4 acc[8];
#pragma unroll
    for (int j = 0; j < 8; ++j) {
        float b = bias[16 * j + m];
        acc[j] = (f32x4){b, b, b, b};
    }

#pragma unroll
    for (int j = 0; j < 8; ++j) {
        int n = 16 * j + m;
#pragma unroll
        for (int ks = 0; ks < KS; ++ks) {
            int k0 = ks * 32 + kg * 8;
            bf16x8 whi = *(const bf16x8*)(Wt + (size_t)n * 128 + k0);
            bf16x8 wlo = *(const bf16x8*)(Wt + 16384 + (size_t)n * 128 + k0);
            acc[j] = __builtin_amdgcn_mfma_f32_16x16x32_bf16(ahi[ks].v, whi, acc[j], 0, 0, 0);
            acc[j] = __builtin_amdgcn_mfma_f32_16x16x32_bf16(alo[ks].v, whi, acc[j], 0, 0, 0);
            acc[j] = __builtin_amdgcn_mfma_f32_16x16x32_bf16(ahi[ks].v, wlo, acc[j], 0, 0, 0);
        }
    }

    // C/D layout: col = lane&15 (=m), row = kg*4 + reg
#pragma unroll
    for (int j = 0; j < 8; ++j) {
        int coln = 16 * j + m;
#pragma unroll
        for (int r = 0; r < 4; ++r) {
            int gr = rowBase + kg * 4 + r;
            if (gr < M) {
                out[(size_t)gr * 128 + coln] = acc[j][r];
                if (BF16OUT) outb[(size_t)gr * 128 + coln] = f2bf(acc[j][r]);
            }
        }
    }

    if (STATS) {
#pragma unroll
        for (int j = 0; j < 8; ++j) {
            float s = 0.f, s2 = 0.f;
#pragma unroll
            for (int r = 0; r < 4; ++r) {
                int gr = rowBase + kg * 4 + r;
                if (gr < M) { float v = acc[j][r]; s += v; s2 += v * v; }
            }
            atomicAdd(&ls[16 * j + m], s);
            atomicAdd(&ls[128 + 16 * j + m], s2);
        }
        __syncthreads();
        atomicAdd(&stats[t], ls[t]);
    }
}

// ---- stats -> affine (for the GEMM-input norm): y = a*x + d --------------
__global__ __launch_bounds__(128) void finalize_kernel(const float* __restrict__ stats,
        const float* __restrict__ w, const float* __restrict__ b, const float* __restrict__ s,
        float* __restrict__ aff, float invN) {
    int c = threadIdx.x;
    float mean = stats[c] * invN;
    float ex2  = stats[128 + c] * invN;
    float sv   = s[c];
    float var  = ex2 - 2.f * sv * mean * mean + sv * sv * mean * mean;
    float a    = w[c] * rsqrtf(var + 1e-5f);
    aff[c]       = a;
    aff[128 + c] = b[c] - a * sv * mean;
}

// ---------------- pooling: mean / sum / max per graph (batch sorted) -------
__global__ __launch_bounds__(256) void pool_kernel(const float* __restrict__ h,
        const unsigned* __restrict__ gptr, float* __restrict__ gout, int G) {
    int g = blockIdx.x * 4 + (threadIdx.x >> 6);
    int lane = threadIdx.x & 63;
    if (g >= G) return;
    unsigned s = gptr[g], e = gptr[g + 1];
    int c = 2 * lane;
    float sx = 0.f, sy = 0.f, mx = -INFINITY, my = -INFINITY;
    for (unsigned n = s; n < e; ++n) {
        float2 v = *(const float2*)(h + (size_t)n * 128 + c);
        sx += v.x; sy += v.y;
        mx = fmaxf(mx, v.x); my = fmaxf(my, v.y);
    }
    float cnt = (float)(e - s);
    float inv = 1.f / fmaxf(cnt, 1.f);
    if (e == s) { mx = 0.f; my = 0.f; }
    float* go = gout + (size_t)g * 384;
    go[c] = sx * inv;       go[c + 1] = sy * inv;
    go[128 + c] = sx;       go[128 + c + 1] = sy;
    go[256 + c] = mx;       go[256 + c + 1] = my;
}

// ---------------- readout head: leaky(g@fc1+b1) @ fc2 + b2 ----------------
__global__ __launch_bounds__(64) void head_kernel(const float* __restrict__ gbuf,
        const float* __restrict__ w1, const float* __restrict__ b1,
        const float* __restrict__ w2, const float* __restrict__ b2,
        float* __restrict__ out, int G) {
    __shared__ float y[64];
    int g = blockIdx.x, t = threadIdx.x;
    const float* row = gbuf + (size_t)g * 384;
    float acc = b1[t];
    for (int k = 0; k < 384; ++k) acc += row[k] * w1[(size_t)k * 64 + t];
    y[t] = lrelu(acc);
    __syncthreads();
    if (t < 3) {
        float o = b2[t];
        for (int k = 0; k < 64; ++k) o += y[k] * w2[k * 3 + t];
        out[(size_t)g * 3 + t] = o;
    }
}

extern "C" void kernel_launch(void* const* d_in, const int* in_sizes, int n_in,
                              void* d_out, int out_size, void* d_ws, size_t ws_size,
                              hipStream_t stream) {
    const float* x       = (const float*)d_in[0];
    const float* W1_0    = (const float*)d_in[2];
    const float* b1_0    = (const float*)d_in[3];
    const float* W1_rest = (const float*)d_in[4];
    const float* b1_rest = (const float*)d_in[5];
    const float* gn_w    = (const float*)d_in[6];
    const float* gn_b    = (const float*)d_in[7];
    const float* gn_s    = (const float*)d_in[8];
    const float* W2      = (const float*)d_in[9];
    const float* b2      = (const float*)d_in[10];
    const float* pn_w    = (const float*)d_in[11];
    const float* pn_b    = (const float*)d_in[12];
    const float* pn_s    = (const float*)d_in[13];
    const float* fc1W    = (const float*)d_in[14];
    const float* fc1b    = (const float*)d_in[15];
    const float* fc2W    = (const float*)d_in[16];
    const float* fc2b    = (const float*)d_in[17];
    const int*   ei      = (const int*)d_in[18];
    const int*   batch   = (const int*)d_in[19];
    float* outp = (float*)d_out;

    const int N = N_NODES, E = N_EDGES, G = N_GRAPHS;
    char* w = (char*)d_ws;
    auto alloc = [&](size_t bytes) -> char* {
        char* p = w; w += (bytes + 255) & ~(size_t)255; return p;
    };
    float*    buf0    = (float*)alloc((size_t)N * 128 * 4);
    float*    buf1    = (float*)alloc((size_t)N * 128 * 4);
    unsigned short* hb0 = (unsigned short*)alloc((size_t)N * 128 * 2);  // bf16 shadow of buf0
    unsigned short* xb  = (unsigned short*)alloc((size_t)N * 48 * 2);   // bf16 shadow of x
    unsigned* row_ptr = (unsigned*)alloc((size_t)(N + 1) * 4);
    unsigned* deg     = (unsigned*)alloc((size_t)N * 4);
    unsigned* cursor  = (unsigned*)alloc((size_t)N * 4);
    unsigned* colb    = (unsigned*)alloc((size_t)E * 4);
    unsigned* ghist   = (unsigned*)alloc((size_t)G * 4);
    unsigned* gptr    = (unsigned*)alloc((size_t)(G + 1) * 4);
    float*    statsA  = (float*)alloc(256 * 4);   // gn (GEMM1 output) stats
    float*    statsB  = (float*)alloc(256 * 4);   // pn (GEMM2 output) stats
    float*    aff_gn  = (float*)alloc(256 * 4);
    float*    gbuf    = (float*)alloc((size_t)G * 384 * 4);
    unsigned short* wt = (unsigned short*)alloc((size_t)8 * 32768 * 2);

    hipMemsetAsync(deg, 0, (size_t)N * 4, stream);
    hipMemsetAsync(cursor, 0, (size_t)N * 4, stream);
    hipMemsetAsync(ghist, 0, (size_t)G * 4, stream);

    // CSR over dst, graph segmentation, W preprocess, x shadow
    hist_kernel<<<(E + 255) / 256, 256, 0, stream>>>(ei + E, deg, E);
    scan_kernel<<<1, 1024, 0, stream>>>(deg, row_ptr, N);
    fill_kernel<<<(E + 255) / 256, 256, 0, stream>>>(ei, row_ptr, cursor, colb, E);
    hist_kernel<<<(N + 255) / 256, 256, 0, stream>>>(batch, ghist, N);
    scan_kernel<<<1, 1024, 0, stream>>>(ghist, gptr, G);
    wsplit_kernel<<<dim3(64, 8), 256, 0, stream>>>(W1_0, W1_rest, W2, wt);
    cast_kernel<<<(N * 48 + 255) / 256, 256, 0, stream>>>(x, xb, N * 48);

    const float invN = 1.f / (float)N;
    int gemm_grid = (N + 63) / 64;
    int agg_grid  = (N + 3) / 4;

    // ---- layer 0 ----
    agg_kernel<48, false><<<agg_grid, 256, 0, stream>>>(xb, 48, row_ptr, colb,
            nullptr, nullptr, nullptr, nullptr, invN, buf1, 128, N);
    hipMemsetAsync(statsA, 0, 1024, stream);
    mgemm_kernel<48, false, true, false><<<gemm_grid, 256, 0, stream>>>(buf1, nullptr, wt, b1_0, buf1, nullptr, statsA, N);
    finalize_kernel<<<1, 128, 0, stream>>>(statsA, gn_w, gn_b, gn_s, aff_gn, invN);
    hipMemsetAsync(statsB, 0, 1024, stream);
    mgemm_kernel<128, true, true, true><<<gemm_grid, 256, 0, stream>>>(buf1, aff_gn, wt + 1 * 32768, b2, buf0, hb0, statsB, N);

    // ---- layers 1..3 ----
    for (int i = 1; i < 4; ++i) {
        agg_kernel<128, true><<<agg_grid, 256, 0, stream>>>(hb0, 128, row_ptr, colb,
                statsB, pn_w + (i - 1) * 128, pn_b + (i - 1) * 128, pn_s + (i - 1) * 128, invN, buf1, 128, N);
        hipMemsetAsync(statsA, 0, 1024, stream);
        mgemm_kernel<128, false, true, false><<<gemm_grid, 256, 0, stream>>>(buf1, nullptr,
                wt + (size_t)(2 * i) * 32768, b1_rest + (size_t)(i - 1) * 128, buf1, nullptr, statsA, N);
        finalize_kernel<<<1, 128, 0, stream>>>(statsA, gn_w + i * 128, gn_b + i * 128, gn_s + i * 128, aff_gn, invN);
        if (i < 3) {
            hipMemsetAsync(statsB, 0, 1024, stream);
            mgemm_kernel<128, true, true, true><<<gemm_grid, 256, 0, stream>>>(buf1, aff_gn,
                    wt + (size_t)(2 * i + 1) * 32768, b2 + (size_t)i * 128, buf0, hb0, statsB, N);
        } else {
            mgemm_kernel<128, true, false, false><<<gemm_grid, 256, 0, stream>>>(buf1, aff_gn,
                    wt + (size_t)7 * 32768, b2 + (size_t)3 * 128, buf0, nullptr, nullptr, N);
        }
    }

    pool_kernel<<<(G + 3) / 4, 256, 0, stream>>>(buf0, gptr, gbuf, G);
    head_kernel<<<G, 64, 0, stream>>>(gbuf, fc1W, fc1b, fc2W, fc2b, outp, G);
}

// Round 4
// 1406.833 us; speedup vs baseline: 1.4016x; 1.0311x over previous
//
#include <hip/hip_runtime.h>
#include <hip/hip_bf16.h>
#include <math.h>

#define N_NODES  100000
#define N_EDGES  1600000
#define N_GRAPHS 4096

typedef __attribute__((ext_vector_type(4))) float f32x4;
typedef __attribute__((ext_vector_type(8))) short bf16x8;

__device__ __forceinline__ float lrelu(float x) { return x > 0.f ? x : 0.01f * x; }

__device__ __forceinline__ unsigned short f2bf(float f) {
    unsigned u = __float_as_uint(f);
    unsigned r = (u + 0x7FFFu + ((u >> 16) & 1u)) >> 16;
    return (unsigned short)r;
}
__device__ __forceinline__ float bf2f(unsigned short h) {
    return __uint_as_float(((unsigned)h) << 16);
}

// ---------------- histogram (counts into cnt via atomics) ----------------
__global__ void hist_kernel(const int* __restrict__ idx, unsigned* __restrict__ cnt, int n) {
    int i = blockIdx.x * 256 + threadIdx.x;
    if (i < n) atomicAdd(&cnt[idx[i]], 1u);
}

// ------- exclusive scan, single block 1024 thr, shuffle-based -------------
__global__ __launch_bounds__(1024) void scan_kernel(const unsigned* __restrict__ in,
                                                    unsigned* __restrict__ out, int n) {
    __shared__ unsigned wsum[16];
    __shared__ unsigned carry_s;
    int t = threadIdx.x, lane = t & 63, wv = t >> 6;
    if (t == 0) carry_s = 0u;
    __syncthreads();
    for (int base = 0; base < n; base += 4096) {
        unsigned carry = carry_s;
        unsigned v[4]; unsigned s = 0u;
#pragma unroll
        for (int i = 0; i < 4; ++i) {
            int idx = base + t * 4 + i;
            v[i] = (idx < n) ? in[idx] : 0u;
            s += v[i];
        }
        unsigned ps = s;
#pragma unroll
        for (int off = 1; off < 64; off <<= 1) {
            unsigned x = __shfl_up(ps, off, 64);
            if (lane >= off) ps += x;
        }
        if (lane == 63) wsum[wv] = ps;
        __syncthreads();
        if (wv == 0 && lane < 16) {
            unsigned pw = wsum[lane];
#pragma unroll
            for (int off = 1; off < 16; off <<= 1) {
                unsigned x = __shfl_up(pw, off, 64);
                if (lane >= off) pw += x;
            }
            wsum[lane] = pw;
        }
        __syncthreads();
        unsigned wbase = wv ? wsum[wv - 1] : 0u;
        unsigned run = carry + wbase + (ps - s);
#pragma unroll
        for (int i = 0; i < 4; ++i) {
            int idx = base + t * 4 + i;
            if (idx < n) out[idx] = run;
            run += v[i];
        }
        unsigned total = wsum[15];
        __syncthreads();
        if (t == 0) carry_s = carry + total;
        __syncthreads();
    }
    if (t == 0) out[n] = carry_s;
}

// ---------------- CSR fill (src list per dst node) ----------------
__global__ void fill_kernel(const int* __restrict__ ei, const unsigned* __restrict__ row_ptr,
                            unsigned* __restrict__ cursor, unsigned* __restrict__ col, int E) {
    int e = blockIdx.x * 256 + threadIdx.x;
    if (e >= E) return;
    int src = ei[e];
    int dst = ei[E + e];
    unsigned p = atomicAdd(&cursor[dst], 1u);
    col[row_ptr[dst] + p] = (unsigned)src;
}

// ---------------- cast x (f32) -> bf16 shadow ----------------
__global__ void cast_kernel(const float* __restrict__ in, unsigned short* __restrict__ outb, int n) {
    int i = blockIdx.x * 256 + threadIdx.x;
    if (i < n) outb[i] = f2bf(in[i]);
}

// ---------------- aggregation: m[n] = T(h[n]) + sum_{j in N(n)} T(h[j]) ----
template<int D, bool ACT>
__global__ __launch_bounds__(256) void agg_kernel(const unsigned short* __restrict__ hb, int ld_in,
        const unsigned* __restrict__ row_ptr, const unsigned* __restrict__ col,
        const float* __restrict__ stats, const float* __restrict__ wp,
        const float* __restrict__ bp, const float* __restrict__ sp, float invN,
        float* __restrict__ out, int ld_out, int n) {
    int node = blockIdx.x * 4 + (threadIdx.x >> 6);
    int lane = threadIdx.x & 63;
    constexpr int C2 = D / 2;
    if (node >= n || lane >= C2) return;
    int c = 2 * lane;
    float a0 = 1.f, a1 = 1.f, d0 = 0.f, d1 = 0.f;
    if (ACT) {
        float mean0 = stats[c] * invN,       mean1 = stats[c + 1] * invN;
        float ex0   = stats[128 + c] * invN, ex1   = stats[129 + c] * invN;
        float s0 = sp[c], s1 = sp[c + 1];
        float var0 = ex0 - 2.f * s0 * mean0 * mean0 + s0 * s0 * mean0 * mean0;
        float var1 = ex1 - 2.f * s1 * mean1 * mean1 + s1 * s1 * mean1 * mean1;
        a0 = wp[c] * rsqrtf(var0 + 1e-5f);
        a1 = wp[c + 1] * rsqrtf(var1 + 1e-5f);
        d0 = bp[c] - a0 * s0 * mean0;
        d1 = bp[c + 1] - a1 * s1 * mean1;
    }
#define LOADU(src) *(const unsigned*)(hb + (size_t)(src) * ld_in + c)
#define TX(u)  (ACT ? lrelu(a0 * bf2f((unsigned short)((u) & 0xffffu)) + d0) : bf2f((unsigned short)((u) & 0xffffu)))
#define TY(u)  (ACT ? lrelu(a1 * bf2f((unsigned short)((u) >> 16)) + d1)    : bf2f((unsigned short)((u) >> 16)))
    unsigned su = LOADU(node);
    float x0 = TX(su), x1 = TY(su);
    float y0 = 0.f, y1 = 0.f, z0 = 0.f, z1 = 0.f, q0 = 0.f, q1 = 0.f;
    unsigned e0 = row_ptr[node], e1 = row_ptr[node + 1];
    unsigned e = e0;
    for (; e + 4 <= e1; e += 4) {
        unsigned s0i = col[e], s1i = col[e + 1], s2i = col[e + 2], s3i = col[e + 3];
        unsigned u0 = LOADU(s0i), u1 = LOADU(s1i), u2 = LOADU(s2i), u3 = LOADU(s3i);
        x0 += TX(u0); x1 += TY(u0);
        y0 += TX(u1); y1 += TY(u1);
        z0 += TX(u2); z1 += TY(u2);
        q0 += TX(u3); q1 += TY(u3);
    }
    for (; e < e1; ++e) {
        unsigned u = LOADU(col[e]);
        x0 += TX(u); x1 += TY(u);
    }
#undef LOADU
#undef TX
#undef TY
    float2 o;
    o.x = (x0 + y0) + (z0 + q0);
    o.y = (x1 + y1) + (z1 + q1);
    *(float2*)(out + (size_t)node * ld_out + c) = o;
}

// ---- W preprocess: transpose + hi/lo bf16 split into wt scratch ----------
__global__ __launch_bounds__(256) void wsplit_kernel(const float* __restrict__ W1_0,
        const float* __restrict__ W1_rest, const float* __restrict__ W2,
        unsigned short* __restrict__ wt) {
    int g = blockIdx.y;
    int i = blockIdx.x * 256 + threadIdx.x;   // i = n*128 + k
    int n = i >> 7, k = i & 127;
    float v = 0.f;
    if (g == 0) { if (k < 48) v = W1_0[k * 128 + n]; }
    else if (g & 1) v = W2[(size_t)((g - 1) >> 1) * 16384 + k * 128 + n];
    else            v = W1_rest[(size_t)((g - 2) >> 1) * 16384 + k * 128 + n];
    unsigned short hi = f2bf(v);
    unsigned short lo = f2bf(v - bf2f(hi));
    size_t base = (size_t)g * 32768;
    wt[base + i] = hi;
    wt[base + 16384 + i] = lo;
}

// ---------------- MFMA GEMM: out[M x 128] = T(A[M x K]) @ W + bias --------
// hi/lo bf16 split (3 MFMA terms) => f32-class accuracy.
// block = 256 thr = 4 waves; wave handles 16 rows x 128 cols.
// Logical col for (lane m, acc j) = 8m+j -> lane owns 8 contiguous cols:
// epilogue stores are 2x f32x4 (+1x uint4 bf16 shadow) per row.
// OUTF32 off where the f32 result is dead (GEMM2 of layers 0..2).
template<int K, bool AFF, bool STATS, bool OUTF32, bool BF16OUT>
__global__ __launch_bounds__(256) void mgemm_kernel(const float* __restrict__ A,
        const float* __restrict__ aff, const unsigned short* __restrict__ Wt,
        const float* __restrict__ bias, float* __restrict__ out,
        unsigned short* __restrict__ outb, float* __restrict__ stats, int M) {
    constexpr int KS = (K + 31) / 32;
    __shared__ float ls[256];
    int t = threadIdx.x;
    if (STATS) { ls[t] = 0.f; __syncthreads(); }
    int lane = t & 63, wid = t >> 6;
    int m = lane & 15, kg = lane >> 4;
    int rowBase = blockIdx.x * 64 + wid * 16;
    int arow = rowBase + m;
    bool rowOK = arow < M;

    union U8 { bf16x8 v; unsigned short u[8]; };
    U8 ahi[KS], alo[KS];
#pragma unroll
    for (int ks = 0; ks < KS; ++ks) {
        int k0 = ks * 32 + kg * 8;
        float x[8];
        if (rowOK && k0 < K) {
            f32x4 p = *(const f32x4*)(A + (size_t)arow * 128 + k0);
            f32x4 q = *(const f32x4*)(A + (size_t)arow * 128 + k0 + 4);
            x[0] = p[0]; x[1] = p[1]; x[2] = p[2]; x[3] = p[3];
            x[4] = q[0]; x[5] = q[1]; x[6] = q[2]; x[7] = q[3];
        } else {
#pragma unroll
            for (int j = 0; j < 8; ++j) x[j] = 0.f;
        }
        if (AFF) {
#pragma unroll
            for (int j = 0; j < 8; ++j)
                x[j] = lrelu(aff[k0 + j] * x[j] + aff[128 + k0 + j]);
        }
#pragma unroll
        for (int j = 0; j < 8; ++j) {
            unsigned short h = f2bf(x[j]);
            ahi[ks].u[j] = h;
            alo[ks].u[j] = f2bf(x[j] - bf2f(h));
        }
    }

    f32x4 acc[8];
#pragma unroll
    for (int j = 0; j < 8; ++j) {
        float b = bias[8 * m + j];
        acc[j] = (f32x4){b, b, b, b};
    }

#pragma unroll
    for (int j = 0; j < 8; ++j) {
        int n = 8 * m + j;   // logical col this lane contributes for MFMA j
#pragma unroll
        for (int ks = 0; ks < KS; ++ks) {
            int k0 = ks * 32 + kg * 8;
            bf16x8 whi = *(const bf16x8*)(Wt + (size_t)n * 128 + k0);
            bf16x8 wlo = *(const bf16x8*)(Wt + 16384 + (size_t)n * 128 + k0);
            acc[j] = __builtin_amdgcn_mfma_f32_16x16x32_bf16(ahi[ks].v, whi, acc[j], 0, 0, 0);
            acc[j] = __builtin_amdgcn_mfma_f32_16x16x32_bf16(alo[ks].v, whi, acc[j], 0, 0, 0);
            acc[j] = __builtin_amdgcn_mfma_f32_16x16x32_bf16(ahi[ks].v, wlo, acc[j], 0, 0, 0);
        }
    }

    // C/D: row = kg*4 + r, this lane's cols = 8m..8m+7 (contiguous)
#pragma unroll
    for (int r = 0; r < 4; ++r) {
        int gr = rowBase + kg * 4 + r;
        if (gr < M) {
            if (OUTF32) {
                f32x4 v0 = {acc[0][r], acc[1][r], acc[2][r], acc[3][r]};
                f32x4 v1 = {acc[4][r], acc[5][r], acc[6][r], acc[7][r]};
                *(f32x4*)(out + (size_t)gr * 128 + 8 * m)     = v0;
                *(f32x4*)(out + (size_t)gr * 128 + 8 * m + 4) = v1;
            }
            if (BF16OUT) {
                uint4 u;
                u.x = (unsigned)f2bf(acc[0][r]) | ((unsigned)f2bf(acc[1][r]) << 16);
                u.y = (unsigned)f2bf(acc[2][r]) | ((unsigned)f2bf(acc[3][r]) << 16);
                u.z = (unsigned)f2bf(acc[4][r]) | ((unsigned)f2bf(acc[5][r]) << 16);
                u.w = (unsigned)f2bf(acc[6][r]) | ((unsigned)f2bf(acc[7][r]) << 16);
                *(uint4*)(outb + (size_t)gr * 128 + 8 * m) = u;
            }
        }
    }

    if (STATS) {
#pragma unroll
        for (int j = 0; j < 8; ++j) {
            float s = 0.f, s2 = 0.f;
#pragma unroll
            for (int r = 0; r < 4; ++r) {
                int gr = rowBase + kg * 4 + r;
                if (gr < M) { float v = acc[j][r]; s += v; s2 += v * v; }
            }
            atomicAdd(&ls[8 * m + j], s);
            atomicAdd(&ls[128 + 8 * m + j], s2);
        }
        __syncthreads();
        atomicAdd(&stats[t], ls[t]);
    }
}

// ---- stats -> affine (for the GEMM-input norm): y = a*x + d --------------
__global__ __launch_bounds__(128) void finalize_kernel(const float* __restrict__ stats,
        const float* __restrict__ w, const float* __restrict__ b, const float* __restrict__ s,
        float* __restrict__ aff, float invN) {
    int c = threadIdx.x;
    float mean = stats[c] * invN;
    float ex2  = stats[128 + c] * invN;
    float sv   = s[c];
    float var  = ex2 - 2.f * sv * mean * mean + sv * sv * mean * mean;
    float a    = w[c] * rsqrtf(var + 1e-5f);
    aff[c]       = a;
    aff[128 + c] = b[c] - a * sv * mean;
}

// ---------------- pooling: mean / sum / max per graph (batch sorted) -------
__global__ __launch_bounds__(256) void pool_kernel(const float* __restrict__ h,
        const unsigned* __restrict__ gptr, float* __restrict__ gout, int G) {
    int g = blockIdx.x * 4 + (threadIdx.x >> 6);
    int lane = threadIdx.x & 63;
    if (g >= G) return;
    unsigned s = gptr[g], e = gptr[g + 1];
    int c = 2 * lane;
    float sx = 0.f, sy = 0.f, mx = -INFINITY, my = -INFINITY;
    for (unsigned n = s; n < e; ++n) {
        float2 v = *(const float2*)(h + (size_t)n * 128 + c);
        sx += v.x; sy += v.y;
        mx = fmaxf(mx, v.x); my = fmaxf(my, v.y);
    }
    float cnt = (float)(e - s);
    float inv = 1.f / fmaxf(cnt, 1.f);
    if (e == s) { mx = 0.f; my = 0.f; }
    float* go = gout + (size_t)g * 384;
    go[c] = sx * inv;       go[c + 1] = sy * inv;
    go[128 + c] = sx;       go[128 + c + 1] = sy;
    go[256 + c] = mx;       go[256 + c + 1] = my;
}

// ---------------- readout head: leaky(g@fc1+b1) @ fc2 + b2 ----------------
__global__ __launch_bounds__(64) void head_kernel(const float* __restrict__ gbuf,
        const float* __restrict__ w1, const float* __restrict__ b1,
        const float* __restrict__ w2, const float* __restrict__ b2,
        float* __restrict__ out, int G) {
    __shared__ float y[64];
    int g = blockIdx.x, t = threadIdx.x;
    const float* row = gbuf + (size_t)g * 384;
    float acc = b1[t];
    for (int k = 0; k < 384; ++k) acc += row[k] * w1[(size_t)k * 64 + t];
    y[t] = lrelu(acc);
    __syncthreads();
    if (t < 3) {
        float o = b2[t];
        for (int k = 0; k < 64; ++k) o += y[k] * w2[k * 3 + t];
        out[(size_t)g * 3 + t] = o;
    }
}

extern "C" void kernel_launch(void* const* d_in, const int* in_sizes, int n_in,
                              void* d_out, int out_size, void* d_ws, size_t ws_size,
                              hipStream_t stream) {
    const float* x       = (const float*)d_in[0];
    const float* W1_0    = (const float*)d_in[2];
    const float* b1_0    = (const float*)d_in[3];
    const float* W1_rest = (const float*)d_in[4];
    const float* b1_rest = (const float*)d_in[5];
    const float* gn_w    = (const float*)d_in[6];
    const float* gn_b    = (const float*)d_in[7];
    const float* gn_s    = (const float*)d_in[8];
    const float* W2      = (const float*)d_in[9];
    const float* b2      = (const float*)d_in[10];
    const float* pn_w    = (const float*)d_in[11];
    const float* pn_b    = (const float*)d_in[12];
    const float* pn_s    = (const float*)d_in[13];
    const float* fc1W    = (const float*)d_in[14];
    const float* fc1b    = (const float*)d_in[15];
    const float* fc2W    = (const float*)d_in[16];
    const float* fc2b    = (const float*)d_in[17];
    const int*   ei      = (const int*)d_in[18];
    const int*   batch   = (const int*)d_in[19];
    float* outp = (float*)d_out;

    const int N = N_NODES, E = N_EDGES, G = N_GRAPHS;
    char* w = (char*)d_ws;
    auto alloc = [&](size_t bytes) -> char* {
        char* p = w; w += (bytes + 255) & ~(size_t)255; return p;
    };
    float*    buf0    = (float*)alloc((size_t)N * 128 * 4);
    float*    buf1    = (float*)alloc((size_t)N * 128 * 4);
    unsigned short* hb0 = (unsigned short*)alloc((size_t)N * 128 * 2);
    unsigned short* xb  = (unsigned short*)alloc((size_t)N * 48 * 2);
    unsigned* row_ptr = (unsigned*)alloc((size_t)(N + 1) * 4);
    unsigned* deg     = (unsigned*)alloc((size_t)N * 4);
    unsigned* cursor  = (unsigned*)alloc((size_t)N * 4);
    unsigned* colb    = (unsigned*)alloc((size_t)E * 4);
    unsigned* ghist   = (unsigned*)alloc((size_t)G * 4);
    unsigned* gptr    = (unsigned*)alloc((size_t)(G + 1) * 4);
    float*    statsA  = (float*)alloc(256 * 4);
    float*    statsB  = (float*)alloc(256 * 4);
    float*    aff_gn  = (float*)alloc(256 * 4);
    float*    gbuf    = (float*)alloc((size_t)G * 384 * 4);
    unsigned short* wt = (unsigned short*)alloc((size_t)8 * 32768 * 2);

    hipMemsetAsync(deg, 0, (size_t)N * 4, stream);
    hipMemsetAsync(cursor, 0, (size_t)N * 4, stream);
    hipMemsetAsync(ghist, 0, (size_t)G * 4, stream);

    hist_kernel<<<(E + 255) / 256, 256, 0, stream>>>(ei + E, deg, E);
    scan_kernel<<<1, 1024, 0, stream>>>(deg, row_ptr, N);
    fill_kernel<<<(E + 255) / 256, 256, 0, stream>>>(ei, row_ptr, cursor, colb, E);
    hist_kernel<<<(N + 255) / 256, 256, 0, stream>>>(batch, ghist, N);
    scan_kernel<<<1, 1024, 0, stream>>>(ghist, gptr, G);
    wsplit_kernel<<<dim3(64, 8), 256, 0, stream>>>(W1_0, W1_rest, W2, wt);
    cast_kernel<<<(N * 48 + 255) / 256, 256, 0, stream>>>(x, xb, N * 48);

    const float invN = 1.f / (float)N;
    int gemm_grid = (N + 63) / 64;
    int agg_grid  = (N + 3) / 4;

    // ---- layer 0 ----
    agg_kernel<48, false><<<agg_grid, 256, 0, stream>>>(xb, 48, row_ptr, colb,
            nullptr, nullptr, nullptr, nullptr, invN, buf1, 128, N);
    hipMemsetAsync(statsA, 0, 1024, stream);
    mgemm_kernel<48, false, true, true, false><<<gemm_grid, 256, 0, stream>>>(
            buf1, nullptr, wt, b1_0, buf1, nullptr, statsA, N);
    finalize_kernel<<<1, 128, 0, stream>>>(statsA, gn_w, gn_b, gn_s, aff_gn, invN);
    hipMemsetAsync(statsB, 0, 1024, stream);
    mgemm_kernel<128, true, true, false, true><<<gemm_grid, 256, 0, stream>>>(
            buf1, aff_gn, wt + 1 * 32768, b2, buf0, hb0, statsB, N);

    // ---- layers 1..3 ----
    for (int i = 1; i < 4; ++i) {
        agg_kernel<128, true><<<agg_grid, 256, 0, stream>>>(hb0, 128, row_ptr, colb,
                statsB, pn_w + (i - 1) * 128, pn_b + (i - 1) * 128, pn_s + (i - 1) * 128, invN, buf1, 128, N);
        hipMemsetAsync(statsA, 0, 1024, stream);
        mgemm_kernel<128, false, true, true, false><<<gemm_grid, 256, 0, stream>>>(
                buf1, nullptr, wt + (size_t)(2 * i) * 32768,
                b1_rest + (size_t)(i - 1) * 128, buf1, nullptr, statsA, N);
        finalize_kernel<<<1, 128, 0, stream>>>(statsA, gn_w + i * 128, gn_b + i * 128, gn_s + i * 128, aff_gn, invN);
        if (i < 3) {
            hipMemsetAsync(statsB, 0, 1024, stream);
            mgemm_kernel<128, true, true, false, true><<<gemm_grid, 256, 0, stream>>>(
                    buf1, aff_gn, wt + (size_t)(2 * i + 1) * 32768,
                    b2 + (size_t)i * 128, buf0, hb0, statsB, N);
        } else {
            mgemm_kernel<128, true, false, true, false><<<gemm_grid, 256, 0, stream>>>(
                    buf1, aff_gn, wt + (size_t)7 * 32768,
                    b2 + (size_t)3 * 128, buf0, nullptr, nullptr, N);
        }
    }

    pool_kernel<<<(G + 3) / 4, 256, 0, stream>>>(buf0, gptr, gbuf, G);
    head_kernel<<<G, 64, 0, stream>>>(gbuf, fc1W, fc1b, fc2W, fc2b, outp, G);
}

// Round 5
// 1036.000 us; speedup vs baseline: 1.9033x; 1.3579x over previous
//
#include <hip/hip_runtime.h>
#include <hip/hip_bf16.h>
#include <math.h>

#define N_NODES  100000
#define N_EDGES  1600000
#define N_GRAPHS 4096

typedef __attribute__((ext_vector_type(4))) float f32x4;
typedef __attribute__((ext_vector_type(8))) short bf16x8;

__device__ __forceinline__ float lrelu(float x) { return fmaxf(x, 0.01f * x); }

__device__ __forceinline__ unsigned short f2bf(float f) {
    unsigned u = __float_as_uint(f);
    unsigned r = (u + 0x7FFFu + ((u >> 16) & 1u)) >> 16;
    return (unsigned short)r;
}
__device__ __forceinline__ float bf2f(unsigned short h) {
    return __uint_as_float(((unsigned)h) << 16);
}

// ---------------- histogram ----------------
__global__ void hist_kernel(const int* __restrict__ idx, unsigned* __restrict__ cnt, int n) {
    int i = blockIdx.x * 256 + threadIdx.x;
    if (i < n) atomicAdd(&cnt[idx[i]], 1u);
}

// ------- exclusive scan, single block 1024 thr, shuffle-based -------------
__global__ __launch_bounds__(1024) void scan_kernel(const unsigned* __restrict__ in,
                                                    unsigned* __restrict__ out, int n) {
    __shared__ unsigned wsum[16];
    __shared__ unsigned carry_s;
    int t = threadIdx.x, lane = t & 63, wv = t >> 6;
    if (t == 0) carry_s = 0u;
    __syncthreads();
    for (int base = 0; base < n; base += 4096) {
        unsigned carry = carry_s;
        unsigned v[4]; unsigned s = 0u;
#pragma unroll
        for (int i = 0; i < 4; ++i) {
            int idx = base + t * 4 + i;
            v[i] = (idx < n) ? in[idx] : 0u;
            s += v[i];
        }
        unsigned ps = s;
#pragma unroll
        for (int off = 1; off < 64; off <<= 1) {
            unsigned x = __shfl_up(ps, off, 64);
            if (lane >= off) ps += x;
        }
        if (lane == 63) wsum[wv] = ps;
        __syncthreads();
        if (wv == 0 && lane < 16) {
            unsigned pw = wsum[lane];
#pragma unroll
            for (int off = 1; off < 16; off <<= 1) {
                unsigned x = __shfl_up(pw, off, 64);
                if (lane >= off) pw += x;
            }
            wsum[lane] = pw;
        }
        __syncthreads();
        unsigned wbase = wv ? wsum[wv - 1] : 0u;
        unsigned run = carry + wbase + (ps - s);
#pragma unroll
        for (int i = 0; i < 4; ++i) {
            int idx = base + t * 4 + i;
            if (idx < n) out[idx] = run;
            run += v[i];
        }
        unsigned total = wsum[15];
        __syncthreads();
        if (t == 0) carry_s = carry + total;
        __syncthreads();
    }
    if (t == 0) out[n] = carry_s;
}

// ---------------- CSR fill ----------------
__global__ void fill_kernel(const int* __restrict__ ei, const unsigned* __restrict__ row_ptr,
                            unsigned* __restrict__ cursor, unsigned* __restrict__ col, int E) {
    int e = blockIdx.x * 256 + threadIdx.x;
    if (e >= E) return;
    int src = ei[e];
    int dst = ei[E + e];
    unsigned p = atomicAdd(&cursor[dst], 1u);
    col[row_ptr[dst] + p] = (unsigned)src;
}

// ---------------- cast x (f32) -> bf16 shadow ----------------
__global__ void cast_kernel(const float* __restrict__ in, unsigned short* __restrict__ outb, int n) {
    int i = blockIdx.x * 256 + threadIdx.x;
    if (i < n) outb[i] = f2bf(in[i]);
}

// ---------------- aggregation: m[n] = T(h[n]) + sum_{j in N(n)} T(h[j]) ----
// gathers from bf16 row-major shadow; writes hi/lo bf16 planes (GEMM A input).
// D = gather feature dim, LDO = output plane leading dim (cols >= D zeroed).
template<int D, int LDO, bool ACT>
__global__ __launch_bounds__(256) void agg_kernel(const unsigned short* __restrict__ hb, int ld_in,
        const unsigned* __restrict__ row_ptr, const unsigned* __restrict__ col,
        const float* __restrict__ stats, const float* __restrict__ wp,
        const float* __restrict__ bp, const float* __restrict__ sp, float invN,
        unsigned short* __restrict__ oph, unsigned short* __restrict__ opl, int n) {
    int node = blockIdx.x * 4 + (threadIdx.x >> 6);
    int l = threadIdx.x & 63;
    if (node >= n || l >= LDO / 2) return;
    int c = 2 * l;
    float ox = 0.f, oy = 0.f;
    if (c < D) {
        float a0 = 1.f, a1 = 1.f, d0 = 0.f, d1 = 0.f;
        if (ACT) {
            float mean0 = stats[c] * invN,       mean1 = stats[c + 1] * invN;
            float ex0   = stats[128 + c] * invN, ex1   = stats[129 + c] * invN;
            float s0 = sp[c], s1 = sp[c + 1];
            float var0 = ex0 - 2.f * s0 * mean0 * mean0 + s0 * s0 * mean0 * mean0;
            float var1 = ex1 - 2.f * s1 * mean1 * mean1 + s1 * s1 * mean1 * mean1;
            a0 = wp[c] * rsqrtf(var0 + 1e-5f);
            a1 = wp[c + 1] * rsqrtf(var1 + 1e-5f);
            d0 = bp[c] - a0 * s0 * mean0;
            d1 = bp[c + 1] - a1 * s1 * mean1;
        }
#define LOADU(src) *(const unsigned*)(hb + (size_t)(src) * ld_in + c)
#define TX(u)  (ACT ? lrelu(a0 * bf2f((unsigned short)((u) & 0xffffu)) + d0) : bf2f((unsigned short)((u) & 0xffffu)))
#define TY(u)  (ACT ? lrelu(a1 * bf2f((unsigned short)((u) >> 16)) + d1)    : bf2f((unsigned short)((u) >> 16)))
        unsigned su = LOADU(node);
        float x0 = TX(su), x1 = TY(su);
        float y0 = 0.f, y1 = 0.f, z0 = 0.f, z1 = 0.f, q0 = 0.f, q1 = 0.f;
        unsigned e0 = row_ptr[node], e1 = row_ptr[node + 1];
        unsigned e = e0;
        for (; e + 4 <= e1; e += 4) {
            unsigned s0i = col[e], s1i = col[e + 1], s2i = col[e + 2], s3i = col[e + 3];
            unsigned u0 = LOADU(s0i), u1 = LOADU(s1i), u2 = LOADU(s2i), u3 = LOADU(s3i);
            x0 += TX(u0); x1 += TY(u0);
            y0 += TX(u1); y1 += TY(u1);
            z0 += TX(u2); z1 += TY(u2);
            q0 += TX(u3); q1 += TY(u3);
        }
        for (; e < e1; ++e) {
            unsigned u = LOADU(col[e]);
            x0 += TX(u); x1 += TY(u);
        }
#undef LOADU
#undef TX
#undef TY
        ox = (x0 + y0) + (z0 + q0);
        oy = (x1 + y1) + (z1 + q1);
    }
    unsigned short h0 = f2bf(ox), h1 = f2bf(oy);
    unsigned short g0 = f2bf(ox - bf2f(h0)), g1 = f2bf(oy - bf2f(h1));
    ((unsigned*)oph)[(size_t)node * (LDO / 2) + l] = (unsigned)h0 | ((unsigned)h1 << 16);
    ((unsigned*)opl)[(size_t)node * (LDO / 2) + l] = (unsigned)g0 | ((unsigned)g1 << 16);
}

// ---- W preprocess: hi/lo bf16 split into FRAGMENT-LINEAR order -----------
// wt[g*32768 + i], i = (((ks*8 + j)*2 + h)*64 + lane)*8 + e
// value = split_h( W_g[ k = ks*32 + (lane>>4)*8 + e ][ n = 8*(lane&15) + j ] )
__global__ __launch_bounds__(256) void wsplit_kernel(const float* __restrict__ W1_0,
        const float* __restrict__ W1_rest, const float* __restrict__ W2,
        unsigned short* __restrict__ wt) {
    int g = blockIdx.y;
    int i = blockIdx.x * 256 + threadIdx.x;   // i < 32768
    int e = i & 7, lane = (i >> 3) & 63, h = (i >> 9) & 1, j = (i >> 10) & 7, ks = i >> 13;
    int m = lane & 15, kg = lane >> 4;
    int k = ks * 32 + kg * 8 + e;
    int n = 8 * m + j;
    float v = 0.f;
    if (g == 0) { if (k < 48) v = W1_0[k * 128 + n]; }
    else if (g & 1) v = W2[(size_t)((g - 1) >> 1) * 16384 + k * 128 + n];
    else            v = W1_rest[(size_t)((g - 2) >> 1) * 16384 + k * 128 + n];
    unsigned short hi = f2bf(v);
    unsigned short out = (h == 0) ? hi : f2bf(v - bf2f(hi));
    wt[(size_t)g * 32768 + i] = out;
}

// ---------------- MFMA GEMM v3 -------------------------------------------
// A given as hi/lo bf16 planes (row-major, leading dim LDA shorts).
// W given fragment-linear (1KB contiguous per wave-load).
// block = 256 thr = 4 waves; wave = 32 rows (2 row-groups) x 128 cols.
// 3-term hi/lo MFMA => f32-class accuracy.
// AFF: reconstruct + GraphNorm affine + lrelu + resplit while loading A.
template<int KS, int LDA, bool AFF, bool STATS, bool OUTF32, bool BF16OUT, bool PLANEOUT>
__global__ __launch_bounds__(256) void mgemm_kernel(
        const unsigned short* __restrict__ Ah, const unsigned short* __restrict__ Al,
        const float* __restrict__ aff, const unsigned short* __restrict__ Wt,
        const float* __restrict__ bias, float* __restrict__ outf,
        unsigned short* __restrict__ outb,
        unsigned short* __restrict__ oph, unsigned short* __restrict__ opl,
        float* __restrict__ stats, int M) {
    __shared__ float ls[256];
    int t = threadIdx.x;
    if (STATS) { ls[t] = 0.f; __syncthreads(); }
    int lane = t & 63, wid = t >> 6;
    int m = lane & 15, kg = lane >> 4;
    int rowBase = blockIdx.x * 128 + wid * 32;

    union U8 { bf16x8 v; unsigned short u[8]; };

    f32x4 acc[2][8];
#pragma unroll
    for (int rg = 0; rg < 2; ++rg)
#pragma unroll
        for (int j = 0; j < 8; ++j) {
            float b = bias[8 * m + j];
            acc[rg][j] = (f32x4){b, b, b, b};
        }

#pragma unroll
    for (int ks = 0; ks < KS; ++ks) {
        int k0 = ks * 32 + kg * 8;
        // per-k affine coefficients (uniform over rows)
        f32x4 aA0, aA1, aD0, aD1;
        if (AFF) {
            aA0 = *(const f32x4*)(aff + k0);
            aA1 = *(const f32x4*)(aff + k0 + 4);
            aD0 = *(const f32x4*)(aff + 128 + k0);
            aD1 = *(const f32x4*)(aff + 128 + k0 + 4);
        }
        U8 ahi[2], alo[2];
#pragma unroll
        for (int rg = 0; rg < 2; ++rg) {
            int row = rowBase + rg * 16 + m;
            U8 hi, lo;
            if (row < M) {
                hi.v = *(const bf16x8*)(Ah + (size_t)row * LDA + k0);
                lo.v = *(const bf16x8*)(Al + (size_t)row * LDA + k0);
            } else {
#pragma unroll
                for (int q = 0; q < 8; ++q) { hi.u[q] = 0; lo.u[q] = 0; }
            }
            if (AFF) {
#pragma unroll
                for (int q = 0; q < 8; ++q) {
                    float aE = (q < 4) ? aA0[q] : aA1[q - 4];
                    float dE = (q < 4) ? aD0[q] : aD1[q - 4];
                    float hF = bf2f(hi.u[q]), lF = bf2f(lo.u[q]);
                    float xv = fmaf(aE, lF, fmaf(aE, hF, dE));
                    xv = lrelu(xv);
                    unsigned short nh = f2bf(xv);
                    ahi[rg].u[q] = nh;
                    alo[rg].u[q] = f2bf(xv - bf2f(nh));
                }
            } else {
                ahi[rg] = hi; alo[rg] = lo;
            }
        }
#pragma unroll
        for (int j = 0; j < 8; ++j) {
            size_t wo = ((size_t)(ks * 8 + j) * 2) * 512 + (size_t)lane * 8;
            bf16x8 whi = *(const bf16x8*)(Wt + wo);
            bf16x8 wlo = *(const bf16x8*)(Wt + wo + 512);
#pragma unroll
            for (int rg = 0; rg < 2; ++rg) {
                acc[rg][j] = __builtin_amdgcn_mfma_f32_16x16x32_bf16(ahi[rg].v, whi, acc[rg][j], 0, 0, 0);
                acc[rg][j] = __builtin_amdgcn_mfma_f32_16x16x32_bf16(alo[rg].v, whi, acc[rg][j], 0, 0, 0);
                acc[rg][j] = __builtin_amdgcn_mfma_f32_16x16x32_bf16(ahi[rg].v, wlo, acc[rg][j], 0, 0, 0);
            }
        }
    }

    // epilogue: row = rowBase + rg*16 + kg*4 + r, cols 8m..8m+7 contiguous
#pragma unroll
    for (int rg = 0; rg < 2; ++rg) {
#pragma unroll
        for (int r = 0; r < 4; ++r) {
            int gr = rowBase + rg * 16 + kg * 4 + r;
            if (gr < M) {
                if (OUTF32) {
                    f32x4 v0 = {acc[rg][0][r], acc[rg][1][r], acc[rg][2][r], acc[rg][3][r]};
                    f32x4 v1 = {acc[rg][4][r], acc[rg][5][r], acc[rg][6][r], acc[rg][7][r]};
                    *(f32x4*)(outf + (size_t)gr * 128 + 8 * m)     = v0;
                    *(f32x4*)(outf + (size_t)gr * 128 + 8 * m + 4) = v1;
                }
                if (BF16OUT) {
                    uint4 u;
                    u.x = (unsigned)f2bf(acc[rg][0][r]) | ((unsigned)f2bf(acc[rg][1][r]) << 16);
                    u.y = (unsigned)f2bf(acc[rg][2][r]) | ((unsigned)f2bf(acc[rg][3][r]) << 16);
                    u.z = (unsigned)f2bf(acc[rg][4][r]) | ((unsigned)f2bf(acc[rg][5][r]) << 16);
                    u.w = (unsigned)f2bf(acc[rg][6][r]) | ((unsigned)f2bf(acc[rg][7][r]) << 16);
                    *(uint4*)(outb + (size_t)gr * 128 + 8 * m) = u;
                }
                if (PLANEOUT) {
                    unsigned short h[8], g[8];
#pragma unroll
                    for (int q = 0; q < 8; ++q) {
                        float v = acc[rg][q][r];
                        h[q] = f2bf(v);
                        g[q] = f2bf(v - bf2f(h[q]));
                    }
                    uint4 uh, ug;
                    uh.x = (unsigned)h[0] | ((unsigned)h[1] << 16);
                    uh.y = (unsigned)h[2] | ((unsigned)h[3] << 16);
                    uh.z = (unsigned)h[4] | ((unsigned)h[5] << 16);
                    uh.w = (unsigned)h[6] | ((unsigned)h[7] << 16);
                    ug.x = (unsigned)g[0] | ((unsigned)g[1] << 16);
                    ug.y = (unsigned)g[2] | ((unsigned)g[3] << 16);
                    ug.z = (unsigned)g[4] | ((unsigned)g[5] << 16);
                    ug.w = (unsigned)g[6] | ((unsigned)g[7] << 16);
                    *(uint4*)(oph + (size_t)gr * 128 + 8 * m) = uh;
                    *(uint4*)(opl + (size_t)gr * 128 + 8 * m) = ug;
                }
            }
        }
    }

    if (STATS) {
#pragma unroll
        for (int j = 0; j < 8; ++j) {
            float s = 0.f, s2 = 0.f;
#pragma unroll
            for (int rg = 0; rg < 2; ++rg)
#pragma unroll
                for (int r = 0; r < 4; ++r) {
                    int gr = rowBase + rg * 16 + kg * 4 + r;
                    if (gr < M) { float v = acc[rg][j][r]; s += v; s2 += v * v; }
                }
            atomicAdd(&ls[8 * m + j], s);
            atomicAdd(&ls[128 + 8 * m + j], s2);
        }
        __syncthreads();
        atomicAdd(&stats[t], ls[t]);
    }
}

// ---- stats -> affine: y = a*x + d ----------------------------------------
__global__ __launch_bounds__(128) void finalize_kernel(const float* __restrict__ stats,
        const float* __restrict__ w, const float* __restrict__ b, const float* __restrict__ s,
        float* __restrict__ aff, float invN) {
    int c = threadIdx.x;
    float mean = stats[c] * invN;
    float ex2  = stats[128 + c] * invN;
    float sv   = s[c];
    float var  = ex2 - 2.f * sv * mean * mean + sv * sv * mean * mean;
    float a    = w[c] * rsqrtf(var + 1e-5f);
    aff[c]       = a;
    aff[128 + c] = b[c] - a * sv * mean;
}

// ---------------- pooling: mean / sum / max per graph ---------------------
__global__ __launch_bounds__(256) void pool_kernel(const float* __restrict__ h,
        const unsigned* __restrict__ gptr, float* __restrict__ gout, int G) {
    int g = blockIdx.x * 4 + (threadIdx.x >> 6);
    int lane = threadIdx.x & 63;
    if (g >= G) return;
    unsigned s = gptr[g], e = gptr[g + 1];
    int c = 2 * lane;
    float sx = 0.f, sy = 0.f, mx = -INFINITY, my = -INFINITY;
    for (unsigned n = s; n < e; ++n) {
        float2 v = *(const float2*)(h + (size_t)n * 128 + c);
        sx += v.x; sy += v.y;
        mx = fmaxf(mx, v.x); my = fmaxf(my, v.y);
    }
    float cnt = (float)(e - s);
    float inv = 1.f / fmaxf(cnt, 1.f);
    if (e == s) { mx = 0.f; my = 0.f; }
    float* go = gout + (size_t)g * 384;
    go[c] = sx * inv;       go[c + 1] = sy * inv;
    go[128 + c] = sx;       go[128 + c + 1] = sy;
    go[256 + c] = mx;       go[256 + c + 1] = my;
}

// ---------------- readout head -------------------------------------------
__global__ __launch_bounds__(64) void head_kernel(const float* __restrict__ gbuf,
        const float* __restrict__ w1, const float* __restrict__ b1,
        const float* __restrict__ w2, const float* __restrict__ b2,
        float* __restrict__ out, int G) {
    __shared__ float y[64];
    int g = blockIdx.x, t = threadIdx.x;
    const float* row = gbuf + (size_t)g * 384;
    float acc = b1[t];
    for (int k = 0; k < 384; ++k) acc += row[k] * w1[(size_t)k * 64 + t];
    y[t] = lrelu(acc);
    __syncthreads();
    if (t < 3) {
        float o = b2[t];
        for (int k = 0; k < 64; ++k) o += y[k] * w2[k * 3 + t];
        out[(size_t)g * 3 + t] = o;
    }
}

extern "C" void kernel_launch(void* const* d_in, const int* in_sizes, int n_in,
                              void* d_out, int out_size, void* d_ws, size_t ws_size,
                              hipStream_t stream) {
    const float* x       = (const float*)d_in[0];
    const float* W1_0    = (const float*)d_in[2];
    const float* b1_0    = (const float*)d_in[3];
    const float* W1_rest = (const float*)d_in[4];
    const float* b1_rest = (const float*)d_in[5];
    const float* gn_w    = (const float*)d_in[6];
    const float* gn_b    = (const float*)d_in[7];
    const float* gn_s    = (const float*)d_in[8];
    const float* W2      = (const float*)d_in[9];
    const float* b2      = (const float*)d_in[10];
    const float* pn_w    = (const float*)d_in[11];
    const float* pn_b    = (const float*)d_in[12];
    const float* pn_s    = (const float*)d_in[13];
    const float* fc1W    = (const float*)d_in[14];
    const float* fc1b    = (const float*)d_in[15];
    const float* fc2W    = (const float*)d_in[16];
    const float* fc2b    = (const float*)d_in[17];
    const int*   ei      = (const int*)d_in[18];
    const int*   batch   = (const int*)d_in[19];
    float* outp = (float*)d_out;

    const int N = N_NODES, E = N_EDGES, G = N_GRAPHS;
    char* w = (char*)d_ws;
    auto alloc = [&](size_t bytes) -> char* {
        char* p = w; w += (bytes + 255) & ~(size_t)255; return p;
    };
    // p1 planes double as: layer-0 agg planes (LD 64, first half) and final f32 buf0
    unsigned short* p1h = (unsigned short*)alloc((size_t)N * 128 * 2);
    unsigned short* p1l = (unsigned short*)alloc((size_t)N * 128 * 2);
    float* buf0 = (float*)p1h;                       // 51.2 MB span of p1h+p1l
    unsigned short* p2h = (unsigned short*)alloc((size_t)N * 128 * 2);
    unsigned short* p2l = (unsigned short*)alloc((size_t)N * 128 * 2);
    unsigned short* hb0 = (unsigned short*)alloc((size_t)N * 128 * 2);
    unsigned short* xb  = (unsigned short*)alloc((size_t)N * 48 * 2);
    unsigned* row_ptr = (unsigned*)alloc((size_t)(N + 1) * 4);
    unsigned* deg     = (unsigned*)alloc((size_t)N * 4);
    unsigned* cursor  = (unsigned*)alloc((size_t)N * 4);
    unsigned* colb    = (unsigned*)alloc((size_t)E * 4);
    unsigned* ghist   = (unsigned*)alloc((size_t)G * 4);
    unsigned* gptr    = (unsigned*)alloc((size_t)(G + 1) * 4);
    float*    statsA  = (float*)alloc(256 * 4);
    float*    statsB  = (float*)alloc(256 * 4);
    float*    aff_gn  = (float*)alloc(256 * 4);
    float*    gbuf    = (float*)alloc((size_t)G * 384 * 4);
    unsigned short* wt = (unsigned short*)alloc((size_t)8 * 32768 * 2);

    hipMemsetAsync(deg, 0, (size_t)N * 4, stream);
    hipMemsetAsync(cursor, 0, (size_t)N * 4, stream);
    hipMemsetAsync(ghist, 0, (size_t)G * 4, stream);

    hist_kernel<<<(E + 255) / 256, 256, 0, stream>>>(ei + E, deg, E);
    scan_kernel<<<1, 1024, 0, stream>>>(deg, row_ptr, N);
    fill_kernel<<<(E + 255) / 256, 256, 0, stream>>>(ei, row_ptr, cursor, colb, E);
    hist_kernel<<<(N + 255) / 256, 256, 0, stream>>>(batch, ghist, N);
    scan_kernel<<<1, 1024, 0, stream>>>(ghist, gptr, G);
    wsplit_kernel<<<dim3(128, 8), 256, 0, stream>>>(W1_0, W1_rest, W2, wt);
    cast_kernel<<<(N * 48 + 255) / 256, 256, 0, stream>>>(x, xb, N * 48);

    const float invN = 1.f / (float)N;
    int gemm_grid = (N + 127) / 128;
    int agg_grid  = (N + 3) / 4;

    // ---- layer 0 (K=48, planes LD 64 aliased into p1) ----
    agg_kernel<48, 64, false><<<agg_grid, 256, 0, stream>>>(xb, 48, row_ptr, colb,
            nullptr, nullptr, nullptr, nullptr, invN, p1h, p1l, N);
    hipMemsetAsync(statsA, 0, 1024, stream);
    mgemm_kernel<2, 64, false, true, false, false, true><<<gemm_grid, 256, 0, stream>>>(
            p1h, p1l, nullptr, wt, b1_0, nullptr, nullptr, p2h, p2l, statsA, N);
    finalize_kernel<<<1, 128, 0, stream>>>(statsA, gn_w, gn_b, gn_s, aff_gn, invN);
    hipMemsetAsync(statsB, 0, 1024, stream);
    mgemm_kernel<4, 128, true, true, false, true, false><<<gemm_grid, 256, 0, stream>>>(
            p2h, p2l, aff_gn, wt + 1 * 32768, b2, nullptr, hb0, nullptr, nullptr, statsB, N);

    // ---- layers 1..3 ----
    for (int i = 1; i < 4; ++i) {
        agg_kernel<128, 128, true><<<agg_grid, 256, 0, stream>>>(hb0, 128, row_ptr, colb,
                statsB, pn_w + (i - 1) * 128, pn_b + (i - 1) * 128, pn_s + (i - 1) * 128, invN,
                p1h, p1l, N);
        hipMemsetAsync(statsA, 0, 1024, stream);
        mgemm_kernel<4, 128, false, true, false, false, true><<<gemm_grid, 256, 0, stream>>>(
                p1h, p1l, nullptr, wt + (size_t)(2 * i) * 32768,
                b1_rest + (size_t)(i - 1) * 128, nullptr, nullptr, p2h, p2l, statsA, N);
        finalize_kernel<<<1, 128, 0, stream>>>(statsA, gn_w + i * 128, gn_b + i * 128, gn_s + i * 128, aff_gn, invN);
        if (i < 3) {
            hipMemsetAsync(statsB, 0, 1024, stream);
            mgemm_kernel<4, 128, true, true, false, true, false><<<gemm_grid, 256, 0, stream>>>(
                    p2h, p2l, aff_gn, wt + (size_t)(2 * i + 1) * 32768,
                    b2 + (size_t)i * 128, nullptr, hb0, nullptr, nullptr, statsB, N);
        } else {
            mgemm_kernel<4, 128, true, false, true, false, false><<<gemm_grid, 256, 0, stream>>>(
                    p2h, p2l, aff_gn, wt + (size_t)7 * 32768,
                    b2 + (size_t)3 * 128, buf0, nullptr, nullptr, nullptr, nullptr, N);
        }
    }

    pool_kernel<<<(G + 3) / 4, 256, 0, stream>>>(buf0, gptr, gbuf, G);
    head_kernel<<<G, 64, 0, stream>>>(gbuf, fc1W, fc1b, fc2W, fc2b, outp, G);
}